// Round 1
// baseline (7137.059 us; speedup 1.0000x reference)
//
#include <hip/hip_runtime.h>

#define NN 100000
#define NE 1600000
#define NP 200000

// ---------------- degree kernels ----------------
__global__ __launch_bounds__(256) void k_init_deg(float* deg) {
  int i = blockIdx.x * 256 + threadIdx.x;
  if (i < NN) deg[i] = 1.0f;
}

__global__ __launch_bounds__(256) void k_count_deg(const int* __restrict__ ei,
                                                   float* __restrict__ deg) {
  int e = blockIdx.x * 256 + threadIdx.x;
  if (e < NE) atomicAdd(&deg[ei[NE + e]], 1.0f);
}

__global__ __launch_bounds__(256) void k_rsqrt(float* deg) {
  int i = blockIdx.x * 256 + threadIdx.x;
  if (i < NN) deg[i] = rsqrtf(deg[i]);
}

// ---------------- fused GEMM ----------------
// T = transform(A) @ W, then scaled by dinv[row]; G = identical copy (agg init).
// transform (TRANS=true): a = relu(dinv[row]*A[row][c] + bprev[c])  (prev layer epilogue)
// A: [NN][128] fp32, W: [128][COUT] fp32.
// Block: 256 threads, 128 rows. LDS: A transposed, exactly 64 KiB.
// Thread tile 8 rows x TN cols; W streamed from global (64KB, L2-hot).
template <int COUT, bool TRANS>
__global__ __launch_bounds__(256) void k_gemm(const float* __restrict__ A,
                                              const float* __restrict__ W,
                                              const float* __restrict__ bprev,
                                              const float* __restrict__ dinv,
                                              float* __restrict__ T,
                                              float* __restrict__ G) {
  constexpr int TN = COUT / 16;
  __shared__ float At[128 * 128];  // [k][r], 64 KiB exactly -> 2 blocks/CU
  const int t = threadIdx.x;
  const int row0 = blockIdx.x * 128;

  // stage A transposed: thread t owns row (t>>1), col half (t&1)*64.
  // LDS write bank = r%32 -> 2-way (free). Global: 16B/lane, lines fully
  // consumed across the 16-iteration loop.
  {
    const int r = t >> 1;
    const int ch = (t & 1) * 64;
    const int row = row0 + r;
    const bool ok = row < NN;
    float s = 0.f;
    if (TRANS && ok) s = dinv[row];
    const float* arow = A + (size_t)row * 128 + ch;
#pragma unroll
    for (int i = 0; i < 16; ++i) {
      float4 v = make_float4(0.f, 0.f, 0.f, 0.f);
      if (ok) {
        v = *(const float4*)(arow + 4 * i);
        if (TRANS) {
          float4 b = *(const float4*)(bprev + ch + 4 * i);
          v.x = fmaxf(fmaf(s, v.x, b.x), 0.f);
          v.y = fmaxf(fmaf(s, v.y, b.y), 0.f);
          v.z = fmaxf(fmaf(s, v.z, b.z), 0.f);
          v.w = fmaxf(fmaf(s, v.w, b.w), 0.f);
        }
      }
      const int c = ch + 4 * i;
      At[(c + 0) * 128 + r] = v.x;
      At[(c + 1) * 128 + r] = v.y;
      At[(c + 2) * 128 + r] = v.z;
      At[(c + 3) * 128 + r] = v.w;
    }
  }
  __syncthreads();

  const int tx = t & 15;   // col group: cols tx*TN .. tx*TN+TN-1
  const int ty = t >> 4;   // row group: rows ty*8 .. ty*8+7
  float acc[8][TN];
#pragma unroll
  for (int r = 0; r < 8; ++r)
#pragma unroll
    for (int c = 0; c < TN; ++c) acc[r][c] = 0.f;

  const float* wp = W + tx * TN;
#pragma unroll 4
  for (int k = 0; k < 128; ++k) {
    float4 a0 = *(const float4*)&At[k * 128 + ty * 8];
    float4 a1 = *(const float4*)&At[k * 128 + ty * 8 + 4];
    float a[8] = {a0.x, a0.y, a0.z, a0.w, a1.x, a1.y, a1.z, a1.w};
    float w[TN];
    float4 w0 = *(const float4*)(wp + k * COUT);
    w[0] = w0.x; w[1] = w0.y; w[2] = w0.z; w[3] = w0.w;
    if constexpr (TN == 8) {
      float4 w1 = *(const float4*)(wp + k * COUT + 4);
      w[4] = w1.x; w[5] = w1.y; w[6] = w1.z; w[7] = w1.w;
    }
#pragma unroll
    for (int r = 0; r < 8; ++r)
#pragma unroll
      for (int c = 0; c < TN; ++c) acc[r][c] = fmaf(a[r], w[c], acc[r][c]);
  }

  // epilogue: scale by dinv[row], dual-write T (message source) + G (agg init)
#pragma unroll
  for (int r = 0; r < 8; ++r) {
    const int row = row0 + ty * 8 + r;
    if (row < NN) {
      const float s = dinv[row];
      float o[TN];
#pragma unroll
      for (int c = 0; c < TN; ++c) o[c] = acc[r][c] * s;
      float4* tp = (float4*)(T + (size_t)row * COUT + tx * TN);
      float4* gp = (float4*)(G + (size_t)row * COUT + tx * TN);
      tp[0] = make_float4(o[0], o[1], o[2], o[3]);
      gp[0] = make_float4(o[0], o[1], o[2], o[3]);
      if constexpr (TN == 8) {
        tp[1] = make_float4(o[4], o[5], o[6], o[7]);
        gp[1] = make_float4(o[4], o[5], o[6], o[7]);
      }
    }
  }
}

// ---------------- edge scatter (atomic segment-sum) ----------------
// G[dst] += T[src] per edge. C/4 float4-lanes per edge.
template <int C>
__global__ __launch_bounds__(256) void k_scatter(const int* __restrict__ ei,
                                                 const float* __restrict__ T,
                                                 float* __restrict__ G) {
  constexpr int Q = C / 4;
  long long tid = (long long)blockIdx.x * 256 + threadIdx.x;
  int e = (int)(tid / Q);
  int q = (int)(tid % Q);
  if (e >= NE) return;
  int src = ei[e];
  int dst = ei[NE + e];
  float4 v = *(const float4*)&T[(size_t)src * C + q * 4];
  float* g = &G[(size_t)dst * C + q * 4];
  atomicAdd(g + 0, v.x);
  atomicAdd(g + 1, v.y);
  atomicAdd(g + 2, v.z);
  atomicAdd(g + 3, v.w);
}

// ---------------- pair decode ----------------
// out[p] = sum_c (dinv[i]*G3[i][c]+b3[c]) * (dinv[j]*G3[j][c]+b3[c]), C=64
__global__ __launch_bounds__(256) void k_decode(const int* __restrict__ ni,
                                                const int* __restrict__ nj,
                                                const float* __restrict__ G3,
                                                const float* __restrict__ dinv,
                                                const float* __restrict__ b3,
                                                float* __restrict__ out) {
  int p = blockIdx.x * 4 + (threadIdx.x >> 6);
  int lane = threadIdx.x & 63;
  if (p >= NP) return;
  int i = ni[p], j = nj[p];
  float hi = fmaf(dinv[i], G3[(size_t)i * 64 + lane], b3[lane]);
  float hj = fmaf(dinv[j], G3[(size_t)j * 64 + lane], b3[lane]);
  float v = hi * hj;
#pragma unroll
  for (int off = 32; off > 0; off >>= 1) v += __shfl_down(v, off, 64);
  if (lane == 0) out[p] = v;
}

extern "C" void kernel_launch(void* const* d_in, const int* in_sizes, int n_in,
                              void* d_out, int out_size, void* d_ws, size_t ws_size,
                              hipStream_t stream) {
  const float* x  = (const float*)d_in[0];
  const int*   ei = (const int*)d_in[1];   // [2][NE]: row0=src, row1=dst
  const int*   ni = (const int*)d_in[2];
  const int*   nj = (const int*)d_in[3];
  const float* W1 = (const float*)d_in[4];
  const float* b1 = (const float*)d_in[5];
  const float* W2 = (const float*)d_in[6];
  const float* b2 = (const float*)d_in[7];
  const float* W3 = (const float*)d_in[8];
  const float* b3 = (const float*)d_in[9];
  float* out = (float*)d_out;

  // workspace carve (fp32): dinv[102400] | B0 | B1 | B2, each NN*128
  float* dinv = (float*)d_ws;
  float* B0 = dinv + 102400;
  float* B1 = B0 + (size_t)NN * 128;
  float* B2 = B1 + (size_t)NN * 128;

  // degree -> dinv_sqrt (in place)
  k_init_deg<<<(NN + 255) / 256, 256, 0, stream>>>(dinv);
  k_count_deg<<<NE / 256, 256, 0, stream>>>(ei, dinv);
  k_rsqrt<<<(NN + 255) / 256, 256, 0, stream>>>(dinv);

  const int GB = (NN + 127) / 128;  // 782 gemm blocks

  // layer 1: T=B0, G=B1
  k_gemm<128, false><<<GB, 256, 0, stream>>>(x, W1, nullptr, dinv, B0, B1);
  k_scatter<128><<<(NE * 32) / 256, 256, 0, stream>>>(ei, B0, B1);
  // layer 2: reads B1 (with relu(dinv*.+b1)), T=B2, G=B0
  k_gemm<128, true><<<GB, 256, 0, stream>>>(B1, W2, b1, dinv, B2, B0);
  k_scatter<128><<<(NE * 32) / 256, 256, 0, stream>>>(ei, B2, B0);
  // layer 3: reads B0 (with relu(dinv*.+b2)), COUT=64, T=B1, G=B2
  k_gemm<64, true><<<GB, 256, 0, stream>>>(B0, W3, b2, dinv, B1, B2);
  k_scatter<64><<<(NE * 16) / 256, 256, 0, stream>>>(ei, B1, B2);
  // decode from B2 (+b3, no relu)
  k_decode<<<NP / 4, 256, 0, stream>>>(ni, nj, B2, dinv, b3, out);
}

// Round 2
// 967.917 us; speedup vs baseline: 7.3736x; 7.3736x over previous
//
#include <hip/hip_runtime.h>

#define NN 100000
#define NE 1600000
#define NP 200000
#define SCANB 512
#define NBLK ((NN + SCANB - 1) / SCANB)  // 196

// ---------------- CSR build: count -> scan -> fill ----------------
__global__ __launch_bounds__(256) void k_zero_cnt(int* cnt) {
  int i = blockIdx.x * 256 + threadIdx.x;
  if (i < NN) cnt[i] = 0;
}

__global__ __launch_bounds__(256) void k_count(const int* __restrict__ ei,
                                               int* __restrict__ cnt) {
  int e = blockIdx.x * 256 + threadIdx.x;
  if (e < NE) atomicAdd(&cnt[ei[NE + e]], 1);
}

__global__ __launch_bounds__(SCANB) void k_part_sum(const int* __restrict__ cnt,
                                                    int* __restrict__ bsum) {
  __shared__ int s[SCANB];
  int i = blockIdx.x * SCANB + threadIdx.x;
  s[threadIdx.x] = (i < NN) ? cnt[i] : 0;
  __syncthreads();
  for (int off = SCANB / 2; off > 0; off >>= 1) {
    if (threadIdx.x < off) s[threadIdx.x] += s[threadIdx.x + off];
    __syncthreads();
  }
  if (threadIdx.x == 0) bsum[blockIdx.x] = s[0];
}

// exclusive scan of bsum[0..NBLK) in place (NBLK=196 <= 256)
__global__ __launch_bounds__(256) void k_scan_bsum(int* bsum) {
  __shared__ int s[256];
  int tid = threadIdx.x;
  int v = (tid < NBLK) ? bsum[tid] : 0;
  s[tid] = v;
  __syncthreads();
  for (int off = 1; off < 256; off <<= 1) {
    int a = (tid >= off) ? s[tid - off] : 0;
    __syncthreads();
    s[tid] += a;
    __syncthreads();
  }
  if (tid < NBLK) bsum[tid] = s[tid] - v;  // exclusive
}

// block exclusive scan + base; writes row_ptr, resets cntcur to cursor start,
// and computes dinv_sqrt = rsqrt(1 + in_degree).
__global__ __launch_bounds__(SCANB) void k_scan_final(int* __restrict__ cntcur,
                                                      const int* __restrict__ bsum,
                                                      int* __restrict__ row_ptr,
                                                      float* __restrict__ dinv) {
  __shared__ int s[SCANB];
  int tid = threadIdx.x;
  int i = blockIdx.x * SCANB + tid;
  int v = (i < NN) ? cntcur[i] : 0;
  s[tid] = v;
  __syncthreads();
  for (int off = 1; off < SCANB; off <<= 1) {
    int a = (tid >= off) ? s[tid - off] : 0;
    __syncthreads();
    s[tid] += a;
    __syncthreads();
  }
  int excl = s[tid] - v + bsum[blockIdx.x];
  if (i <= NN) row_ptr[i] = excl;
  if (i < NN) {
    cntcur[i] = excl;  // cursor for fill
    dinv[i] = rsqrtf((float)(v + 1));
  }
}

__global__ __launch_bounds__(256) void k_fill(const int* __restrict__ ei,
                                              int* __restrict__ cursor,
                                              int* __restrict__ col) {
  int e = blockIdx.x * 256 + threadIdx.x;
  if (e < NE) {
    int dst = ei[NE + e];
    int pos = atomicAdd(&cursor[dst], 1);
    col[pos] = ei[e];  // src
  }
}

// ---------------- fused GEMM ----------------
// T[row] = transform(A[row]) @ W * dinv[row]
// transform (TRANS): relu(dinv[row]*A[row][c] + bprev[c])  (prev-layer epilogue)
template <int COUT, bool TRANS>
__global__ __launch_bounds__(256) void k_gemm(const float* __restrict__ A,
                                              const float* __restrict__ W,
                                              const float* __restrict__ bprev,
                                              const float* __restrict__ dinv,
                                              float* __restrict__ T) {
  constexpr int TN = COUT / 16;
  __shared__ float At[128 * 128];  // [k][r], 64 KiB -> 2 blocks/CU
  const int t = threadIdx.x;
  const int row0 = blockIdx.x * 128;

  {
    const int r = t >> 1;
    const int ch = (t & 1) * 64;
    const int row = row0 + r;
    const bool ok = row < NN;
    float s = 0.f;
    if (TRANS && ok) s = dinv[row];
    const float* arow = A + (size_t)row * 128 + ch;
#pragma unroll
    for (int i = 0; i < 16; ++i) {
      float4 v = make_float4(0.f, 0.f, 0.f, 0.f);
      if (ok) {
        v = *(const float4*)(arow + 4 * i);
        if (TRANS) {
          float4 b = *(const float4*)(bprev + ch + 4 * i);
          v.x = fmaxf(fmaf(s, v.x, b.x), 0.f);
          v.y = fmaxf(fmaf(s, v.y, b.y), 0.f);
          v.z = fmaxf(fmaf(s, v.z, b.z), 0.f);
          v.w = fmaxf(fmaf(s, v.w, b.w), 0.f);
        }
      }
      const int c = ch + 4 * i;
      At[(c + 0) * 128 + r] = v.x;
      At[(c + 1) * 128 + r] = v.y;
      At[(c + 2) * 128 + r] = v.z;
      At[(c + 3) * 128 + r] = v.w;
    }
  }
  __syncthreads();

  const int tx = t & 15;
  const int ty = t >> 4;
  float acc[8][TN];
#pragma unroll
  for (int r = 0; r < 8; ++r)
#pragma unroll
    for (int c = 0; c < TN; ++c) acc[r][c] = 0.f;

  const float* wp = W + tx * TN;
#pragma unroll 4
  for (int k = 0; k < 128; ++k) {
    float4 a0 = *(const float4*)&At[k * 128 + ty * 8];
    float4 a1 = *(const float4*)&At[k * 128 + ty * 8 + 4];
    float a[8] = {a0.x, a0.y, a0.z, a0.w, a1.x, a1.y, a1.z, a1.w};
    float w[TN];
    float4 w0 = *(const float4*)(wp + k * COUT);
    w[0] = w0.x; w[1] = w0.y; w[2] = w0.z; w[3] = w0.w;
    if constexpr (TN == 8) {
      float4 w1 = *(const float4*)(wp + k * COUT + 4);
      w[4] = w1.x; w[5] = w1.y; w[6] = w1.z; w[7] = w1.w;
    }
#pragma unroll
    for (int r = 0; r < 8; ++r)
#pragma unroll
      for (int c = 0; c < TN; ++c) acc[r][c] = fmaf(a[r], w[c], acc[r][c]);
  }

#pragma unroll
  for (int r = 0; r < 8; ++r) {
    const int row = row0 + ty * 8 + r;
    if (row < NN) {
      const float s = dinv[row];
      float4* tp = (float4*)(T + (size_t)row * COUT + tx * TN);
      tp[0] = make_float4(acc[r][0] * s, acc[r][1] * s, acc[r][2] * s, acc[r][3] * s);
      if constexpr (TN == 8)
        tp[1] = make_float4(acc[r][4] * s, acc[r][5] * s, acc[r][6] * s, acc[r][7] * s);
    }
  }
}

// ---------------- node-centric gather (no atomics) ----------------
// G[i] = T[i] + sum_{e in CSR[i]} T[col[e]]. One wave per node.
template <int C>
__global__ __launch_bounds__(256) void k_gather(const int* __restrict__ row_ptr,
                                                const int* __restrict__ col,
                                                const float* __restrict__ T,
                                                float* __restrict__ G) {
  int w = (blockIdx.x * 256 + threadIdx.x) >> 6;
  int lane = threadIdx.x & 63;
  if (w >= NN) return;
  int s = row_ptr[w], t = row_ptr[w + 1];
  if constexpr (C == 128) {
    const float2* T2 = (const float2*)T;
    float2 acc = T2[(size_t)w * 64 + lane];
    int e = s;
    int src = (e < t) ? col[e] : 0;
    while (e < t) {
      int nsrc = (e + 1 < t) ? col[e + 1] : 0;  // prefetch next index
      float2 v = T2[(size_t)src * 64 + lane];
      acc.x += v.x;
      acc.y += v.y;
      src = nsrc;
      ++e;
    }
    ((float2*)G)[(size_t)w * 64 + lane] = acc;
  } else {
    float acc = T[(size_t)w * 64 + lane];
    int e = s;
    int src = (e < t) ? col[e] : 0;
    while (e < t) {
      int nsrc = (e + 1 < t) ? col[e + 1] : 0;
      acc += T[(size_t)src * 64 + lane];
      src = nsrc;
      ++e;
    }
    G[(size_t)w * 64 + lane] = acc;
  }
}

// ---------------- pair decode ----------------
__global__ __launch_bounds__(256) void k_decode(const int* __restrict__ ni,
                                                const int* __restrict__ nj,
                                                const float* __restrict__ G3,
                                                const float* __restrict__ dinv,
                                                const float* __restrict__ b3,
                                                float* __restrict__ out) {
  int p = blockIdx.x * 4 + (threadIdx.x >> 6);
  int lane = threadIdx.x & 63;
  if (p >= NP) return;
  int i = ni[p], j = nj[p];
  float hi = fmaf(dinv[i], G3[(size_t)i * 64 + lane], b3[lane]);
  float hj = fmaf(dinv[j], G3[(size_t)j * 64 + lane], b3[lane]);
  float v = hi * hj;
#pragma unroll
  for (int off = 32; off > 0; off >>= 1) v += __shfl_down(v, off, 64);
  if (lane == 0) out[p] = v;
}

extern "C" void kernel_launch(void* const* d_in, const int* in_sizes, int n_in,
                              void* d_out, int out_size, void* d_ws, size_t ws_size,
                              hipStream_t stream) {
  const float* x  = (const float*)d_in[0];
  const int*   ei = (const int*)d_in[1];  // [2][NE]: row0=src, row1=dst
  const int*   ni = (const int*)d_in[2];
  const int*   nj = (const int*)d_in[3];
  const float* W1 = (const float*)d_in[4];
  const float* b1 = (const float*)d_in[5];
  const float* W2 = (const float*)d_in[6];
  const float* b2 = (const float*)d_in[7];
  const float* W3 = (const float*)d_in[8];
  const float* b3 = (const float*)d_in[9];
  float* out = (float*)d_out;

  // ws carve (all chunks 1KiB-aligned)
  float* dinv    = (float*)d_ws;              // 102400 f
  int*   cntcur  = (int*)(dinv + 102400);     // 102400 i (count, then cursor)
  int*   row_ptr = cntcur + 102400;           // 102400 i (NN+1 used)
  int*   bsum    = row_ptr + 102400;          // 256 i
  int*   col     = bsum + 256;                // NE i
  float* B0      = (float*)(col + NE);        // NN*128 f
  float* B1      = B0 + (size_t)NN * 128;
  float* B2      = B1 + (size_t)NN * 128;

  // ---- CSR build + dinv ----
  k_zero_cnt<<<(NN + 255) / 256, 256, 0, stream>>>(cntcur);
  k_count<<<NE / 256, 256, 0, stream>>>(ei, cntcur);
  k_part_sum<<<NBLK, SCANB, 0, stream>>>(cntcur, bsum);
  k_scan_bsum<<<1, 256, 0, stream>>>(bsum);
  k_scan_final<<<NBLK, SCANB, 0, stream>>>(cntcur, bsum, row_ptr, dinv);
  k_fill<<<NE / 256, 256, 0, stream>>>(ei, cntcur, col);

  const int GB = (NN + 127) / 128;          // 782
  const int GATB = (NN * 64) / 256 + 1;     // 25001 blocks (4 waves each)

  // layer 1
  k_gemm<128, false><<<GB, 256, 0, stream>>>(x, W1, nullptr, dinv, B0);
  k_gather<128><<<GATB, 256, 0, stream>>>(row_ptr, col, B0, B1);
  // layer 2
  k_gemm<128, true><<<GB, 256, 0, stream>>>(B1, W2, b1, dinv, B2);
  k_gather<128><<<GATB, 256, 0, stream>>>(row_ptr, col, B2, B0);
  // layer 3 (COUT=64)
  k_gemm<64, true><<<GB, 256, 0, stream>>>(B0, W3, b2, dinv, B1);
  k_gather<64><<<GATB, 256, 0, stream>>>(row_ptr, col, B1, B2);
  // decode
  k_decode<<<NP / 4, 256, 0, stream>>>(ni, nj, B2, dinv, b3, out);
}

// Round 3
// 801.263 us; speedup vs baseline: 8.9073x; 1.2080x over previous
//
#include <hip/hip_runtime.h>

#define NN 100000
#define NE 1600000
#define NP 200000
#define SCANB 512
#define NBLK ((NN + SCANB - 1) / SCANB)  // 196

// ---------------- CSR build: count -> scan -> fill ----------------
__global__ __launch_bounds__(256) void k_zero_cnt(int* cnt) {
  int i = blockIdx.x * 256 + threadIdx.x;
  if (i < NN) cnt[i] = 0;
}

__global__ __launch_bounds__(256) void k_count(const int* __restrict__ ei,
                                               int* __restrict__ cnt) {
  int e = blockIdx.x * 256 + threadIdx.x;
  if (e < NE) atomicAdd(&cnt[ei[NE + e]], 1);
}

__global__ __launch_bounds__(SCANB) void k_part_sum(const int* __restrict__ cnt,
                                                    int* __restrict__ bsum) {
  __shared__ int s[SCANB];
  int i = blockIdx.x * SCANB + threadIdx.x;
  s[threadIdx.x] = (i < NN) ? cnt[i] : 0;
  __syncthreads();
  for (int off = SCANB / 2; off > 0; off >>= 1) {
    if (threadIdx.x < off) s[threadIdx.x] += s[threadIdx.x + off];
    __syncthreads();
  }
  if (threadIdx.x == 0) bsum[blockIdx.x] = s[0];
}

// exclusive scan of bsum[0..NBLK) in place (NBLK=196 <= 256)
__global__ __launch_bounds__(256) void k_scan_bsum(int* bsum) {
  __shared__ int s[256];
  int tid = threadIdx.x;
  int v = (tid < NBLK) ? bsum[tid] : 0;
  s[tid] = v;
  __syncthreads();
  for (int off = 1; off < 256; off <<= 1) {
    int a = (tid >= off) ? s[tid - off] : 0;
    __syncthreads();
    s[tid] += a;
    __syncthreads();
  }
  if (tid < NBLK) bsum[tid] = s[tid] - v;  // exclusive
}

__global__ __launch_bounds__(SCANB) void k_scan_final(int* __restrict__ cntcur,
                                                      const int* __restrict__ bsum,
                                                      int* __restrict__ row_ptr,
                                                      float* __restrict__ dinv) {
  __shared__ int s[SCANB];
  int tid = threadIdx.x;
  int i = blockIdx.x * SCANB + tid;
  int v = (i < NN) ? cntcur[i] : 0;
  s[tid] = v;
  __syncthreads();
  for (int off = 1; off < SCANB; off <<= 1) {
    int a = (tid >= off) ? s[tid - off] : 0;
    __syncthreads();
    s[tid] += a;
    __syncthreads();
  }
  int excl = s[tid] - v + bsum[blockIdx.x];
  if (i <= NN) row_ptr[i] = excl;
  if (i < NN) {
    cntcur[i] = excl;  // cursor for fill
    dinv[i] = rsqrtf((float)(v + 1));
  }
}

__global__ __launch_bounds__(256) void k_fill(const int* __restrict__ ei,
                                              int* __restrict__ cursor,
                                              int* __restrict__ col) {
  int e = blockIdx.x * 256 + threadIdx.x;
  if (e < NE) {
    int dst = ei[NE + e];
    int pos = atomicAdd(&cursor[dst], 1);
    col[pos] = ei[e];  // src
  }
}

// ---------------- fused GEMM ----------------
template <int COUT, bool TRANS>
__global__ __launch_bounds__(256) void k_gemm(const float* __restrict__ A,
                                              const float* __restrict__ W,
                                              const float* __restrict__ bprev,
                                              const float* __restrict__ dinv,
                                              float* __restrict__ T) {
  constexpr int TN = COUT / 16;
  __shared__ float At[128 * 128];  // [k][r], 64 KiB -> 2 blocks/CU
  const int t = threadIdx.x;
  const int row0 = blockIdx.x * 128;

  {
    const int r = t >> 1;
    const int ch = (t & 1) * 64;
    const int row = row0 + r;
    const bool ok = row < NN;
    float s = 0.f;
    if (TRANS && ok) s = dinv[row];
    const float* arow = A + (size_t)row * 128 + ch;
#pragma unroll
    for (int i = 0; i < 16; ++i) {
      float4 v = make_float4(0.f, 0.f, 0.f, 0.f);
      if (ok) {
        v = *(const float4*)(arow + 4 * i);
        if (TRANS) {
          float4 b = *(const float4*)(bprev + ch + 4 * i);
          v.x = fmaxf(fmaf(s, v.x, b.x), 0.f);
          v.y = fmaxf(fmaf(s, v.y, b.y), 0.f);
          v.z = fmaxf(fmaf(s, v.z, b.z), 0.f);
          v.w = fmaxf(fmaf(s, v.w, b.w), 0.f);
        }
      }
      const int c = ch + 4 * i;
      At[(c + 0) * 128 + r] = v.x;
      At[(c + 1) * 128 + r] = v.y;
      At[(c + 2) * 128 + r] = v.z;
      At[(c + 3) * 128 + r] = v.w;
    }
  }
  __syncthreads();

  const int tx = t & 15;
  const int ty = t >> 4;
  float acc[8][TN];
#pragma unroll
  for (int r = 0; r < 8; ++r)
#pragma unroll
    for (int c = 0; c < TN; ++c) acc[r][c] = 0.f;

  const float* wp = W + tx * TN;
#pragma unroll 4
  for (int k = 0; k < 128; ++k) {
    float4 a0 = *(const float4*)&At[k * 128 + ty * 8];
    float4 a1 = *(const float4*)&At[k * 128 + ty * 8 + 4];
    float a[8] = {a0.x, a0.y, a0.z, a0.w, a1.x, a1.y, a1.z, a1.w};
    float w[TN];
    float4 w0 = *(const float4*)(wp + k * COUT);
    w[0] = w0.x; w[1] = w0.y; w[2] = w0.z; w[3] = w0.w;
    if constexpr (TN == 8) {
      float4 w1 = *(const float4*)(wp + k * COUT + 4);
      w[4] = w1.x; w[5] = w1.y; w[6] = w1.z; w[7] = w1.w;
    }
#pragma unroll
    for (int r = 0; r < 8; ++r)
#pragma unroll
      for (int c = 0; c < TN; ++c) acc[r][c] = fmaf(a[r], w[c], acc[r][c]);
  }

#pragma unroll
  for (int r = 0; r < 8; ++r) {
    const int row = row0 + ty * 8 + r;
    if (row < NN) {
      const float s = dinv[row];
      float4* tp = (float4*)(T + (size_t)row * COUT + tx * TN);
      tp[0] = make_float4(acc[r][0] * s, acc[r][1] * s, acc[r][2] * s, acc[r][3] * s);
      if constexpr (TN == 8)
        tp[1] = make_float4(acc[r][4] * s, acc[r][5] * s, acc[r][6] * s, acc[r][7] * s);
    }
  }
}

// ---------------- node-centric gather, high-MLP version ----------------
// G[i] = T[i] + sum_{e in CSR[i]} T[col[e]]. One wave per node.
// C=128: two half-waves (32 lanes x float4) process 2 edges in parallel,
//        4-deep unroll -> 8 independent 512B row-loads in flight per wave.
// C=64:  four quarter-waves (16 lanes x float4), 4 edges parallel, unroll 2.
template <int C>
__global__ __launch_bounds__(256) void k_gather(const int* __restrict__ row_ptr,
                                                const int* __restrict__ col,
                                                const float* __restrict__ T,
                                                float* __restrict__ G) {
  int w = (blockIdx.x * 256 + threadIdx.x) >> 6;
  int lane = threadIdx.x & 63;
  if (w >= NN) return;
  int s = row_ptr[w], t = row_ptr[w + 1];
  const float4* T4 = (const float4*)T;

  if constexpr (C == 128) {
    const int h = lane >> 5;   // half-wave id: 0,1
    const int cl = lane & 31;  // float4 column within row
    float4 acc = make_float4(0.f, 0.f, 0.f, 0.f);
    if (h == 0) acc = T4[(size_t)w * 32 + cl];  // self-loop term
    int e = s + h;
    for (; e + 6 < t; e += 8) {  // edges e, e+2, e+4, e+6 for this half
      int c0 = col[e], c1 = col[e + 2], c2 = col[e + 4], c3 = col[e + 6];
      float4 v0 = T4[(size_t)c0 * 32 + cl];
      float4 v1 = T4[(size_t)c1 * 32 + cl];
      float4 v2 = T4[(size_t)c2 * 32 + cl];
      float4 v3 = T4[(size_t)c3 * 32 + cl];
      acc.x += (v0.x + v1.x) + (v2.x + v3.x);
      acc.y += (v0.y + v1.y) + (v2.y + v3.y);
      acc.z += (v0.z + v1.z) + (v2.z + v3.z);
      acc.w += (v0.w + v1.w) + (v2.w + v3.w);
    }
    for (; e < t; e += 2) {
      float4 v = T4[(size_t)col[e] * 32 + cl];
      acc.x += v.x; acc.y += v.y; acc.z += v.z; acc.w += v.w;
    }
    acc.x += __shfl_down(acc.x, 32, 64);
    acc.y += __shfl_down(acc.y, 32, 64);
    acc.z += __shfl_down(acc.z, 32, 64);
    acc.w += __shfl_down(acc.w, 32, 64);
    if (h == 0) ((float4*)G)[(size_t)w * 32 + cl] = acc;
  } else {
    const int q = lane >> 4;   // quarter-wave id: 0..3
    const int cl = lane & 15;  // float4 column within 64-ch row
    float4 acc = make_float4(0.f, 0.f, 0.f, 0.f);
    if (q == 0) acc = T4[(size_t)w * 16 + cl];
    int e = s + q;
    for (; e + 4 < t; e += 8) {  // edges e, e+4 for this quarter
      int c0 = col[e], c1 = col[e + 4];
      float4 v0 = T4[(size_t)c0 * 16 + cl];
      float4 v1 = T4[(size_t)c1 * 16 + cl];
      acc.x += v0.x + v1.x;
      acc.y += v0.y + v1.y;
      acc.z += v0.z + v1.z;
      acc.w += v0.w + v1.w;
    }
    for (; e < t; e += 4) {
      float4 v = T4[(size_t)col[e] * 16 + cl];
      acc.x += v.x; acc.y += v.y; acc.z += v.z; acc.w += v.w;
    }
    acc.x += __shfl_down(acc.x, 16, 64);
    acc.y += __shfl_down(acc.y, 16, 64);
    acc.z += __shfl_down(acc.z, 16, 64);
    acc.w += __shfl_down(acc.w, 16, 64);
    acc.x += __shfl_down(acc.x, 32, 64);
    acc.y += __shfl_down(acc.y, 32, 64);
    acc.z += __shfl_down(acc.z, 32, 64);
    acc.w += __shfl_down(acc.w, 32, 64);
    if (q == 0) ((float4*)G)[(size_t)w * 16 + cl] = acc;
  }
}

// ---------------- pair decode ----------------
__global__ __launch_bounds__(256) void k_decode(const int* __restrict__ ni,
                                                const int* __restrict__ nj,
                                                const float* __restrict__ G3,
                                                const float* __restrict__ dinv,
                                                const float* __restrict__ b3,
                                                float* __restrict__ out) {
  int p = blockIdx.x * 4 + (threadIdx.x >> 6);
  int lane = threadIdx.x & 63;
  if (p >= NP) return;
  int i = ni[p], j = nj[p];
  float hi = fmaf(dinv[i], G3[(size_t)i * 64 + lane], b3[lane]);
  float hj = fmaf(dinv[j], G3[(size_t)j * 64 + lane], b3[lane]);
  float v = hi * hj;
#pragma unroll
  for (int off = 32; off > 0; off >>= 1) v += __shfl_down(v, off, 64);
  if (lane == 0) out[p] = v;
}

extern "C" void kernel_launch(void* const* d_in, const int* in_sizes, int n_in,
                              void* d_out, int out_size, void* d_ws, size_t ws_size,
                              hipStream_t stream) {
  const float* x  = (const float*)d_in[0];
  const int*   ei = (const int*)d_in[1];  // [2][NE]: row0=src, row1=dst
  const int*   ni = (const int*)d_in[2];
  const int*   nj = (const int*)d_in[3];
  const float* W1 = (const float*)d_in[4];
  const float* b1 = (const float*)d_in[5];
  const float* W2 = (const float*)d_in[6];
  const float* b2 = (const float*)d_in[7];
  const float* W3 = (const float*)d_in[8];
  const float* b3 = (const float*)d_in[9];
  float* out = (float*)d_out;

  // ws carve
  float* dinv    = (float*)d_ws;              // 102400 f
  int*   cntcur  = (int*)(dinv + 102400);     // 102400 i
  int*   row_ptr = cntcur + 102400;           // 102400 i
  int*   bsum    = row_ptr + 102400;          // 256 i
  int*   col     = bsum + 256;                // NE i
  float* B0      = (float*)(col + NE);        // NN*128 f
  float* B1      = B0 + (size_t)NN * 128;
  float* B2      = B1 + (size_t)NN * 128;

  // ---- CSR build + dinv ----
  k_zero_cnt<<<(NN + 255) / 256, 256, 0, stream>>>(cntcur);
  k_count<<<NE / 256, 256, 0, stream>>>(ei, cntcur);
  k_part_sum<<<NBLK, SCANB, 0, stream>>>(cntcur, bsum);
  k_scan_bsum<<<1, 256, 0, stream>>>(bsum);
  k_scan_final<<<NBLK, SCANB, 0, stream>>>(cntcur, bsum, row_ptr, dinv);
  k_fill<<<NE / 256, 256, 0, stream>>>(ei, cntcur, col);

  const int GB = (NN + 127) / 128;             // 782
  const int GATB = (NN * 64 + 255) / 256;      // 25000 blocks (4 waves each)

  // layer 1
  k_gemm<128, false><<<GB, 256, 0, stream>>>(x, W1, nullptr, dinv, B0);
  k_gather<128><<<GATB, 256, 0, stream>>>(row_ptr, col, B0, B1);
  // layer 2
  k_gemm<128, true><<<GB, 256, 0, stream>>>(B1, W2, b1, dinv, B2);
  k_gather<128><<<GATB, 256, 0, stream>>>(row_ptr, col, B2, B0);
  // layer 3 (COUT=64)
  k_gemm<64, true><<<GB, 256, 0, stream>>>(B0, W3, b2, dinv, B1);
  k_gather<64><<<GATB, 256, 0, stream>>>(row_ptr, col, B1, B2);
  // decode
  k_decode<<<NP / 4, 256, 0, stream>>>(ni, nj, B2, dinv, b3, out);
}

// Round 4
// 659.281 us; speedup vs baseline: 10.8255x; 1.2154x over previous
//
#include <hip/hip_runtime.h>

#define NN 100000
#define NE 1600000
#define NP 200000
#define SCANB 512
#define NBLK ((NN + SCANB - 1) / SCANB)  // 196
#define NBKT 782                          // buckets of 128 nodes: (NN+127)/128
#define BCAP 3072                         // per-bucket arena capacity (mean 2046, sigma 45)
#define BKB 4096                          // edges per k_bucket block

// ---------------- bucket-sort CSR build ----------------
__global__ __launch_bounds__(256) void k_init_gcur(int* gcur) {
  int i = blockIdx.x * 256 + threadIdx.x;
  if (i < 1024) gcur[i] = i * BCAP;
}

// Phase A: LDS counting-sort of 4096-edge chunks by coarse bucket (dst>>7),
// flush contiguous per-bucket runs to aux arena. All global writes are runs.
__global__ __launch_bounds__(256) void k_bucket(const int* __restrict__ ei,
                                                int* __restrict__ gcur,
                                                int* __restrict__ aux) {
  __shared__ int cnt[1024];
  __shared__ int scn[1024];
  __shared__ int cur[1024];   // scatter cursors, then reused as global bases
  __shared__ int sc[256];
  __shared__ int sorted[BKB];
  __shared__ unsigned short sbkt[BKB];
  const int t = threadIdx.x;
  const int base = blockIdx.x * BKB;

  for (int i = t; i < 1024; i += 256) cnt[i] = 0;
  __syncthreads();

  int pk[16], bk[16];
#pragma unroll
  for (int i = 0; i < 16; ++i) {
    int e = base + t + 256 * i;  // coalesced
    if (e < NE) {
      int src = ei[e], dst = ei[NE + e];
      bk[i] = dst >> 7;
      pk[i] = src | ((dst & 127) << 17);  // 17b src | 7b dst_local
      atomicAdd(&cnt[bk[i]], 1);
    } else {
      bk[i] = -1;
    }
  }
  __syncthreads();

  // exclusive scan of cnt[1024], 4 per thread
  int s0 = cnt[4 * t], s1 = cnt[4 * t + 1], s2 = cnt[4 * t + 2], s3 = cnt[4 * t + 3];
  int local = s0 + s1 + s2 + s3;
  sc[t] = local;
  __syncthreads();
  for (int off = 1; off < 256; off <<= 1) {
    int a = (t >= off) ? sc[t - off] : 0;
    __syncthreads();
    sc[t] += a;
    __syncthreads();
  }
  int b0 = sc[t] - local;
  scn[4 * t] = b0;
  scn[4 * t + 1] = b0 + s0;
  scn[4 * t + 2] = b0 + s0 + s1;
  scn[4 * t + 3] = b0 + s0 + s1 + s2;
  cur[4 * t] = scn[4 * t];
  cur[4 * t + 1] = scn[4 * t + 1];
  cur[4 * t + 2] = scn[4 * t + 2];
  cur[4 * t + 3] = scn[4 * t + 3];
  __syncthreads();
  const int tot = sc[255];

  // scatter into block-sorted order (LDS random: cheap)
#pragma unroll
  for (int i = 0; i < 16; ++i) {
    if (bk[i] >= 0) {
      int pos = atomicAdd(&cur[bk[i]], 1);
      sorted[pos] = pk[i];
      sbkt[pos] = (unsigned short)bk[i];
    }
  }
  __syncthreads();

  // one global-cursor atomic per touched bucket; reuse cur[] as global base
  for (int b = t; b < 1024; b += 256) {
    int c = cnt[b];
    if (c > 0) cur[b] = atomicAdd(&gcur[b], c);
  }
  __syncthreads();

  // coalesced-run flush
  for (int k = t; k < tot; k += 256) {
    int b = sbkt[k];
    aux[cur[b] + (k - scn[b])] = sorted[k];
  }
}

// Phase B1: per-bucket node-degree counts via LDS atomics, coalesced cnt write.
__global__ __launch_bounds__(256) void k_bktcount(const int* __restrict__ gcur,
                                                  const int* __restrict__ aux,
                                                  int* __restrict__ cnt) {
  __shared__ int c[128];
  const int b = blockIdx.x, t = threadIdx.x;
  if (t < 128) c[t] = 0;
  __syncthreads();
  const int m = gcur[b] - b * BCAP;
  const int* a = aux + (size_t)b * BCAP;
  for (int k = t; k < m; k += 256) atomicAdd(&c[a[k] >> 17], 1);
  __syncthreads();
  int node = b * 128 + t;
  if (t < 128 && node < NN) cnt[node] = c[t];
}

// Phase B2: fine sort within bucket via LDS cursors; col writes land densely
// in the block's private ~8KB segment (L2-hot, full-line writebacks).
__global__ __launch_bounds__(256) void k_bktsort(const int* __restrict__ gcur,
                                                 const int* __restrict__ aux,
                                                 const int* __restrict__ row_ptr,
                                                 int* __restrict__ col) {
  __shared__ int cur[128];
  const int b = blockIdx.x, t = threadIdx.x;
  int node = b * 128 + t;
  if (t < 128) cur[t] = (node < NN) ? row_ptr[node] : 0;
  __syncthreads();
  const int m = gcur[b] - b * BCAP;
  const int* a = aux + (size_t)b * BCAP;
  for (int k = t; k < m; k += 256) {
    int p = a[k];
    int pos = atomicAdd(&cur[p >> 17], 1);
    col[pos] = p & 0x1FFFF;
  }
}

// ---------------- scans ----------------
__global__ __launch_bounds__(SCANB) void k_part_sum(const int* __restrict__ cnt,
                                                    int* __restrict__ bsum) {
  __shared__ int s[SCANB];
  int i = blockIdx.x * SCANB + threadIdx.x;
  s[threadIdx.x] = (i < NN) ? cnt[i] : 0;
  __syncthreads();
  for (int off = SCANB / 2; off > 0; off >>= 1) {
    if (threadIdx.x < off) s[threadIdx.x] += s[threadIdx.x + off];
    __syncthreads();
  }
  if (threadIdx.x == 0) bsum[blockIdx.x] = s[0];
}

__global__ __launch_bounds__(256) void k_scan_bsum(int* bsum) {
  __shared__ int s[256];
  int tid = threadIdx.x;
  int v = (tid < NBLK) ? bsum[tid] : 0;
  s[tid] = v;
  __syncthreads();
  for (int off = 1; off < 256; off <<= 1) {
    int a = (tid >= off) ? s[tid - off] : 0;
    __syncthreads();
    s[tid] += a;
    __syncthreads();
  }
  if (tid < NBLK) bsum[tid] = s[tid] - v;  // exclusive
}

__global__ __launch_bounds__(SCANB) void k_scan_final(const int* __restrict__ cnt,
                                                      const int* __restrict__ bsum,
                                                      int* __restrict__ row_ptr,
                                                      float* __restrict__ dinv) {
  __shared__ int s[SCANB];
  int tid = threadIdx.x;
  int i = blockIdx.x * SCANB + tid;
  int v = (i < NN) ? cnt[i] : 0;
  s[tid] = v;
  __syncthreads();
  for (int off = 1; off < SCANB; off <<= 1) {
    int a = (tid >= off) ? s[tid - off] : 0;
    __syncthreads();
    s[tid] += a;
    __syncthreads();
  }
  int excl = s[tid] - v + bsum[blockIdx.x];
  if (i <= NN) row_ptr[i] = excl;
  if (i < NN) dinv[i] = rsqrtf((float)(v + 1));
}

// ---------------- fused GEMM ----------------
template <int COUT, bool TRANS>
__global__ __launch_bounds__(256) void k_gemm(const float* __restrict__ A,
                                              const float* __restrict__ W,
                                              const float* __restrict__ bprev,
                                              const float* __restrict__ dinv,
                                              float* __restrict__ T) {
  constexpr int TN = COUT / 16;
  __shared__ float At[128 * 128];  // [k][r], 64 KiB -> 2 blocks/CU
  const int t = threadIdx.x;
  const int row0 = blockIdx.x * 128;

  {
    const int r = t >> 1;
    const int ch = (t & 1) * 64;
    const int row = row0 + r;
    const bool ok = row < NN;
    float s = 0.f;
    if (TRANS && ok) s = dinv[row];
    const float* arow = A + (size_t)row * 128 + ch;
#pragma unroll
    for (int i = 0; i < 16; ++i) {
      float4 v = make_float4(0.f, 0.f, 0.f, 0.f);
      if (ok) {
        v = *(const float4*)(arow + 4 * i);
        if (TRANS) {
          float4 b = *(const float4*)(bprev + ch + 4 * i);
          v.x = fmaxf(fmaf(s, v.x, b.x), 0.f);
          v.y = fmaxf(fmaf(s, v.y, b.y), 0.f);
          v.z = fmaxf(fmaf(s, v.z, b.z), 0.f);
          v.w = fmaxf(fmaf(s, v.w, b.w), 0.f);
        }
      }
      const int c = ch + 4 * i;
      At[(c + 0) * 128 + r] = v.x;
      At[(c + 1) * 128 + r] = v.y;
      At[(c + 2) * 128 + r] = v.z;
      At[(c + 3) * 128 + r] = v.w;
    }
  }
  __syncthreads();

  const int tx = t & 15;
  const int ty = t >> 4;
  float acc[8][TN];
#pragma unroll
  for (int r = 0; r < 8; ++r)
#pragma unroll
    for (int c = 0; c < TN; ++c) acc[r][c] = 0.f;

  const float* wp = W + tx * TN;
#pragma unroll 4
  for (int k = 0; k < 128; ++k) {
    float4 a0 = *(const float4*)&At[k * 128 + ty * 8];
    float4 a1 = *(const float4*)&At[k * 128 + ty * 8 + 4];
    float a[8] = {a0.x, a0.y, a0.z, a0.w, a1.x, a1.y, a1.z, a1.w};
    float w[TN];
    float4 w0 = *(const float4*)(wp + k * COUT);
    w[0] = w0.x; w[1] = w0.y; w[2] = w0.z; w[3] = w0.w;
    if constexpr (TN == 8) {
      float4 w1 = *(const float4*)(wp + k * COUT + 4);
      w[4] = w1.x; w[5] = w1.y; w[6] = w1.z; w[7] = w1.w;
    }
#pragma unroll
    for (int r = 0; r < 8; ++r)
#pragma unroll
      for (int c = 0; c < TN; ++c) acc[r][c] = fmaf(a[r], w[c], acc[r][c]);
  }

#pragma unroll
  for (int r = 0; r < 8; ++r) {
    const int row = row0 + ty * 8 + r;
    if (row < NN) {
      const float s = dinv[row];
      float4* tp = (float4*)(T + (size_t)row * COUT + tx * TN);
      tp[0] = make_float4(acc[r][0] * s, acc[r][1] * s, acc[r][2] * s, acc[r][3] * s);
      if constexpr (TN == 8)
        tp[1] = make_float4(acc[r][4] * s, acc[r][5] * s, acc[r][6] * s, acc[r][7] * s);
    }
  }
}

// ---------------- node-centric gather, high-MLP ----------------
template <int C>
__global__ __launch_bounds__(256) void k_gather(const int* __restrict__ row_ptr,
                                                const int* __restrict__ col,
                                                const float* __restrict__ T,
                                                float* __restrict__ G) {
  int w = (blockIdx.x * 256 + threadIdx.x) >> 6;
  int lane = threadIdx.x & 63;
  if (w >= NN) return;
  int s = row_ptr[w], t = row_ptr[w + 1];
  const float4* T4 = (const float4*)T;

  if constexpr (C == 128) {
    const int h = lane >> 5;
    const int cl = lane & 31;
    float4 acc = make_float4(0.f, 0.f, 0.f, 0.f);
    if (h == 0) acc = T4[(size_t)w * 32 + cl];  // self-loop
    int e = s + h;
    for (; e + 6 < t; e += 8) {
      int c0 = col[e], c1 = col[e + 2], c2 = col[e + 4], c3 = col[e + 6];
      float4 v0 = T4[(size_t)c0 * 32 + cl];
      float4 v1 = T4[(size_t)c1 * 32 + cl];
      float4 v2 = T4[(size_t)c2 * 32 + cl];
      float4 v3 = T4[(size_t)c3 * 32 + cl];
      acc.x += (v0.x + v1.x) + (v2.x + v3.x);
      acc.y += (v0.y + v1.y) + (v2.y + v3.y);
      acc.z += (v0.z + v1.z) + (v2.z + v3.z);
      acc.w += (v0.w + v1.w) + (v2.w + v3.w);
    }
    for (; e < t; e += 2) {
      float4 v = T4[(size_t)col[e] * 32 + cl];
      acc.x += v.x; acc.y += v.y; acc.z += v.z; acc.w += v.w;
    }
    acc.x += __shfl_down(acc.x, 32, 64);
    acc.y += __shfl_down(acc.y, 32, 64);
    acc.z += __shfl_down(acc.z, 32, 64);
    acc.w += __shfl_down(acc.w, 32, 64);
    if (h == 0) ((float4*)G)[(size_t)w * 32 + cl] = acc;
  } else {
    const int q = lane >> 4;
    const int cl = lane & 15;
    float4 acc = make_float4(0.f, 0.f, 0.f, 0.f);
    if (q == 0) acc = T4[(size_t)w * 16 + cl];
    int e = s + q;
    for (; e + 4 < t; e += 8) {
      int c0 = col[e], c1 = col[e + 4];
      float4 v0 = T4[(size_t)c0 * 16 + cl];
      float4 v1 = T4[(size_t)c1 * 16 + cl];
      acc.x += v0.x + v1.x;
      acc.y += v0.y + v1.y;
      acc.z += v0.z + v1.z;
      acc.w += v0.w + v1.w;
    }
    for (; e < t; e += 4) {
      float4 v = T4[(size_t)col[e] * 16 + cl];
      acc.x += v.x; acc.y += v.y; acc.z += v.z; acc.w += v.w;
    }
    acc.x += __shfl_down(acc.x, 16, 64);
    acc.y += __shfl_down(acc.y, 16, 64);
    acc.z += __shfl_down(acc.z, 16, 64);
    acc.w += __shfl_down(acc.w, 16, 64);
    acc.x += __shfl_down(acc.x, 32, 64);
    acc.y += __shfl_down(acc.y, 32, 64);
    acc.z += __shfl_down(acc.z, 32, 64);
    acc.w += __shfl_down(acc.w, 32, 64);
    if (q == 0) ((float4*)G)[(size_t)w * 16 + cl] = acc;
  }
}

// ---------------- pair decode ----------------
__global__ __launch_bounds__(256) void k_decode(const int* __restrict__ ni,
                                                const int* __restrict__ nj,
                                                const float* __restrict__ G3,
                                                const float* __restrict__ dinv,
                                                const float* __restrict__ b3,
                                                float* __restrict__ out) {
  int p = blockIdx.x * 4 + (threadIdx.x >> 6);
  int lane = threadIdx.x & 63;
  if (p >= NP) return;
  int i = ni[p], j = nj[p];
  float hi = fmaf(dinv[i], G3[(size_t)i * 64 + lane], b3[lane]);
  float hj = fmaf(dinv[j], G3[(size_t)j * 64 + lane], b3[lane]);
  float v = hi * hj;
#pragma unroll
  for (int off = 32; off > 0; off >>= 1) v += __shfl_down(v, off, 64);
  if (lane == 0) out[p] = v;
}

extern "C" void kernel_launch(void* const* d_in, const int* in_sizes, int n_in,
                              void* d_out, int out_size, void* d_ws, size_t ws_size,
                              hipStream_t stream) {
  const float* x  = (const float*)d_in[0];
  const int*   ei = (const int*)d_in[1];  // [2][NE]: row0=src, row1=dst
  const int*   ni = (const int*)d_in[2];
  const int*   nj = (const int*)d_in[3];
  const float* W1 = (const float*)d_in[4];
  const float* b1 = (const float*)d_in[5];
  const float* W2 = (const float*)d_in[6];
  const float* b2 = (const float*)d_in[7];
  const float* W3 = (const float*)d_in[8];
  const float* b3 = (const float*)d_in[9];
  float* out = (float*)d_out;

  // ws carve
  float* dinv    = (float*)d_ws;              // 102400 f
  int*   cnt     = (int*)(dinv + 102400);     // 102400 i
  int*   row_ptr = cnt + 102400;              // 102400 i (NN+1 used)
  int*   bsum    = row_ptr + 102400;          // 256 i
  int*   gcur    = bsum + 256;                // 1024 i
  int*   col     = gcur + 1024;               // NE i
  float* B0      = (float*)(col + NE);        // NN*128 f
  float* B1      = B0 + (size_t)NN * 128;
  float* B2      = B1 + (size_t)NN * 128;
  int*   aux     = (int*)B2;  // 12.6 MB arena, dead before gemm2 writes B2

  // ---- CSR build + dinv (bucket sort, coalesced writes only) ----
  k_init_gcur<<<4, 256, 0, stream>>>(gcur);
  k_bucket<<<(NE + BKB - 1) / BKB, 256, 0, stream>>>(ei, gcur, aux);
  k_bktcount<<<NBKT, 256, 0, stream>>>(gcur, aux, cnt);
  k_part_sum<<<NBLK, SCANB, 0, stream>>>(cnt, bsum);
  k_scan_bsum<<<1, 256, 0, stream>>>(bsum);
  k_scan_final<<<NBLK, SCANB, 0, stream>>>(cnt, bsum, row_ptr, dinv);
  k_bktsort<<<NBKT, 256, 0, stream>>>(gcur, aux, row_ptr, col);

  const int GB = (NN + 127) / 128;         // 782
  const int GATB = (NN * 64 + 255) / 256;  // 25000

  // layer 1
  k_gemm<128, false><<<GB, 256, 0, stream>>>(x, W1, nullptr, dinv, B0);
  k_gather<128><<<GATB, 256, 0, stream>>>(row_ptr, col, B0, B1);
  // layer 2
  k_gemm<128, true><<<GB, 256, 0, stream>>>(B1, W2, b1, dinv, B2);
  k_gather<128><<<GATB, 256, 0, stream>>>(row_ptr, col, B2, B0);
  // layer 3 (COUT=64)
  k_gemm<64, true><<<GB, 256, 0, stream>>>(B0, W3, b2, dinv, B1);
  k_gather<64><<<GATB, 256, 0, stream>>>(row_ptr, col, B1, B2);
  // decode
  k_decode<<<NP / 4, 256, 0, stream>>>(ni, nj, B2, dinv, b3, out);
}

// Round 5
// 401.412 us; speedup vs baseline: 17.7799x; 1.6424x over previous
//
#include <hip/hip_runtime.h>

#define NN 100000
#define NNP 100032   // padded to 1563*64 rows so GEMM tiles never go OOB in ws
#define NE 1600000
#define NP 200000
#define SCANB 512
#define NBLK ((NN + SCANB - 1) / SCANB)  // 196
#define NBKT 782
#define BCAP 3072
#define BKB 4096

typedef short s16x8 __attribute__((ext_vector_type(8)));
typedef float f32x4 __attribute__((ext_vector_type(4)));

__device__ __forceinline__ unsigned short f2bf(float f) {  // RNE fp32->bf16
  unsigned int u = __float_as_uint(f);
  u += 0x7fffu + ((u >> 16) & 1u);
  return (unsigned short)(u >> 16);
}

// ---------------- bucket-sort CSR build (unchanged from R4) ----------------
__global__ __launch_bounds__(256) void k_init_gcur(int* gcur) {
  int i = blockIdx.x * 256 + threadIdx.x;
  if (i < 1024) gcur[i] = i * BCAP;
}

__global__ __launch_bounds__(256) void k_bucket(const int* __restrict__ ei,
                                                int* __restrict__ gcur,
                                                int* __restrict__ aux) {
  __shared__ int cnt[1024];
  __shared__ int scn[1024];
  __shared__ int cur[1024];
  __shared__ int sc[256];
  __shared__ int sorted[BKB];
  __shared__ unsigned short sbkt[BKB];
  const int t = threadIdx.x;
  const int base = blockIdx.x * BKB;

  for (int i = t; i < 1024; i += 256) cnt[i] = 0;
  __syncthreads();

  int pk[16], bk[16];
#pragma unroll
  for (int i = 0; i < 16; ++i) {
    int e = base + t + 256 * i;
    if (e < NE) {
      int src = ei[e], dst = ei[NE + e];
      bk[i] = dst >> 7;
      pk[i] = src | ((dst & 127) << 17);
      atomicAdd(&cnt[bk[i]], 1);
    } else {
      bk[i] = -1;
    }
  }
  __syncthreads();

  int s0 = cnt[4 * t], s1 = cnt[4 * t + 1], s2 = cnt[4 * t + 2], s3 = cnt[4 * t + 3];
  int local = s0 + s1 + s2 + s3;
  sc[t] = local;
  __syncthreads();
  for (int off = 1; off < 256; off <<= 1) {
    int a = (t >= off) ? sc[t - off] : 0;
    __syncthreads();
    sc[t] += a;
    __syncthreads();
  }
  int b0 = sc[t] - local;
  scn[4 * t] = b0;
  scn[4 * t + 1] = b0 + s0;
  scn[4 * t + 2] = b0 + s0 + s1;
  scn[4 * t + 3] = b0 + s0 + s1 + s2;
  cur[4 * t] = scn[4 * t];
  cur[4 * t + 1] = scn[4 * t + 1];
  cur[4 * t + 2] = scn[4 * t + 2];
  cur[4 * t + 3] = scn[4 * t + 3];
  __syncthreads();
  const int tot = sc[255];

#pragma unroll
  for (int i = 0; i < 16; ++i) {
    if (bk[i] >= 0) {
      int pos = atomicAdd(&cur[bk[i]], 1);
      sorted[pos] = pk[i];
      sbkt[pos] = (unsigned short)bk[i];
    }
  }
  __syncthreads();

  for (int b = t; b < 1024; b += 256) {
    int c = cnt[b];
    if (c > 0) cur[b] = atomicAdd(&gcur[b], c);
  }
  __syncthreads();

  for (int k = t; k < tot; k += 256) {
    int b = sbkt[k];
    aux[cur[b] + (k - scn[b])] = sorted[k];
  }
}

__global__ __launch_bounds__(256) void k_bktcount(const int* __restrict__ gcur,
                                                  const int* __restrict__ aux,
                                                  int* __restrict__ cnt) {
  __shared__ int c[128];
  const int b = blockIdx.x, t = threadIdx.x;
  if (t < 128) c[t] = 0;
  __syncthreads();
  const int m = gcur[b] - b * BCAP;
  const int* a = aux + (size_t)b * BCAP;
  for (int k = t; k < m; k += 256) atomicAdd(&c[a[k] >> 17], 1);
  __syncthreads();
  int node = b * 128 + t;
  if (t < 128 && node < NN) cnt[node] = c[t];
}

__global__ __launch_bounds__(256) void k_bktsort(const int* __restrict__ gcur,
                                                 const int* __restrict__ aux,
                                                 const int* __restrict__ row_ptr,
                                                 int* __restrict__ col) {
  __shared__ int cur[128];
  const int b = blockIdx.x, t = threadIdx.x;
  int node = b * 128 + t;
  if (t < 128) cur[t] = (node < NN) ? row_ptr[node] : 0;
  __syncthreads();
  const int m = gcur[b] - b * BCAP;
  const int* a = aux + (size_t)b * BCAP;
  for (int k = t; k < m; k += 256) {
    int p = a[k];
    int pos = atomicAdd(&cur[p >> 17], 1);
    col[pos] = p & 0x1FFFF;
  }
}

// ---------------- scans ----------------
__global__ __launch_bounds__(SCANB) void k_part_sum(const int* __restrict__ cnt,
                                                    int* __restrict__ bsum) {
  __shared__ int s[SCANB];
  int i = blockIdx.x * SCANB + threadIdx.x;
  s[threadIdx.x] = (i < NN) ? cnt[i] : 0;
  __syncthreads();
  for (int off = SCANB / 2; off > 0; off >>= 1) {
    if (threadIdx.x < off) s[threadIdx.x] += s[threadIdx.x + off];
    __syncthreads();
  }
  if (threadIdx.x == 0) bsum[blockIdx.x] = s[0];
}

__global__ __launch_bounds__(256) void k_scan_bsum(int* bsum) {
  __shared__ int s[256];
  int tid = threadIdx.x;
  int v = (tid < NBLK) ? bsum[tid] : 0;
  s[tid] = v;
  __syncthreads();
  for (int off = 1; off < 256; off <<= 1) {
    int a = (tid >= off) ? s[tid - off] : 0;
    __syncthreads();
    s[tid] += a;
    __syncthreads();
  }
  if (tid < NBLK) bsum[tid] = s[tid] - v;
}

__global__ __launch_bounds__(SCANB) void k_scan_final(const int* __restrict__ cnt,
                                                      const int* __restrict__ bsum,
                                                      int* __restrict__ row_ptr,
                                                      float* __restrict__ dinv) {
  __shared__ int s[SCANB];
  int tid = threadIdx.x;
  int i = blockIdx.x * SCANB + tid;
  int v = (i < NN) ? cnt[i] : 0;
  s[tid] = v;
  __syncthreads();
  for (int off = 1; off < SCANB; off <<= 1) {
    int a = (tid >= off) ? s[tid - off] : 0;
    __syncthreads();
    s[tid] += a;
    __syncthreads();
  }
  int excl = s[tid] - v + bsum[blockIdx.x];
  if (i <= NN) row_ptr[i] = excl;
  if (i < NN) dinv[i] = rsqrtf((float)(v + 1));
}

// ---------------- W pre-pack: fp32 [128][COUT] -> MFMA B-frag layout bf16 ----
// Wt uint4[(ks*NT+tl)*64 + lane] = 8 bf16: W[ks*32 + (lane>>4)*8 + j][tl*16 + (lane&15)]
template <int NT>
__global__ __launch_bounds__(256) void k_prepw(const float* __restrict__ W,
                                               uint* __restrict__ Wt) {
  constexpr int COUT = NT * 16;
  int tid = blockIdx.x * 256 + threadIdx.x;
  if (tid >= 4 * NT * 64) return;
  int lane = tid & 63, comb = tid >> 6;
  int ks = comb / NT, tl = comb % NT;
  int q = lane >> 4, n = lane & 15;
  uint w[4];
#pragma unroll
  for (int jj = 0; jj < 4; ++jj) {
    int k0 = ks * 32 + q * 8 + 2 * jj;
    uint lo = f2bf(W[k0 * COUT + tl * 16 + n]);
    uint hi = f2bf(W[(k0 + 1) * COUT + tl * 16 + n]);
    w[jj] = lo | (hi << 16);
  }
  uint4* dst = (uint4*)Wt;
  dst[comb * 64 + lane] = make_uint4(w[0], w[1], w[2], w[3]);
}

// ---------------- MFMA GEMM: T[r] = (A@W)[r] * dinv[r], bf16 out ----------
// Block = 4 waves, tile 64 rows x COUT. A read straight from global (bf16 or
// fp32-with-cast), W frags via LDS, epilogue bounces through LDS for
// coalesced bf16 row-major stores.
template <int COUT, bool AFP32>
__global__ __launch_bounds__(256) void k_gemm_mfma(const void* __restrict__ Av,
                                                   const uint* __restrict__ Wt,
                                                   const float* __restrict__ dinv,
                                                   unsigned short* __restrict__ T) {
  constexpr int NT = COUT / 16;
  __shared__ __align__(16) uint Wlds[4 * NT * 64 * 4];     // 4*NT KB
  __shared__ __align__(16) unsigned short Obuf[64 * COUT];  // 64 rows bf16
  const int t = threadIdx.x;
  {
    const uint4* src = (const uint4*)Wt;
    uint4* dst = (uint4*)Wlds;
    for (int i = t; i < 4 * NT * 64; i += 256) dst[i] = src[i];
  }
  __syncthreads();

  const int wv = t >> 6, lane = t & 63;
  const int n = lane & 15, quad = lane >> 4;
  const int rt = blockIdx.x;
  const int rbase = rt * 64 + wv * 16;

  union AB { uint4 u; s16x8 s; };
  AB a[4];
  if constexpr (AFP32) {
    const float* A = (const float*)Av;
    int row = rbase + n;
    if (row >= NN) row = NN - 1;  // input x is exactly NN rows
    const float* ap = A + (size_t)row * 128;
#pragma unroll
    for (int ks = 0; ks < 4; ++ks) {
      float4 v0 = *(const float4*)(ap + ks * 32 + quad * 8);
      float4 v1 = *(const float4*)(ap + ks * 32 + quad * 8 + 4);
      a[ks].u.x = (uint)f2bf(v0.x) | ((uint)f2bf(v0.y) << 16);
      a[ks].u.y = (uint)f2bf(v0.z) | ((uint)f2bf(v0.w) << 16);
      a[ks].u.z = (uint)f2bf(v1.x) | ((uint)f2bf(v1.y) << 16);
      a[ks].u.w = (uint)f2bf(v1.z) | ((uint)f2bf(v1.w) << 16);
    }
  } else {
    const uint4* A = (const uint4*)Av;  // bf16 rows, 16 uint4 per 128-ch row
    int row = rbase + n;                // ws rows padded to NNP: always in-bounds
#pragma unroll
    for (int ks = 0; ks < 4; ++ks) a[ks].u = A[(size_t)row * 16 + ks * 4 + quad];
  }

  f32x4 acc[NT];
#pragma unroll
  for (int tl = 0; tl < NT; ++tl) acc[tl] = (f32x4){0.f, 0.f, 0.f, 0.f};

#pragma unroll
  for (int ks = 0; ks < 4; ++ks) {
#pragma unroll
    for (int tl = 0; tl < NT; ++tl) {
      AB b;
      b.u = *(const uint4*)&Wlds[((ks * NT + tl) * 64 + lane) * 4];
      acc[tl] = __builtin_amdgcn_mfma_f32_16x16x32_bf16(a[ks].s, b.s, acc[tl], 0, 0, 0);
    }
  }

  // epilogue: scale rows by dinv, bf16, LDS bounce, coalesced store
  float4 dv = *(const float4*)(dinv + rbase + quad * 4);
  float dvv[4] = {dv.x, dv.y, dv.z, dv.w};
  unsigned short* ob = Obuf + wv * 16 * COUT;
#pragma unroll
  for (int tl = 0; tl < NT; ++tl)
#pragma unroll
    for (int r = 0; r < 4; ++r)
      ob[(quad * 4 + r) * COUT + tl * 16 + n] = f2bf(acc[tl][r] * dvv[r]);

  // wave-private slice: no __syncthreads needed (compiler orders LDS ops)
  uint4* gdst = (uint4*)(T + (size_t)rbase * COUT);
  constexpr int ITER = COUT / 32;  // 16B chunks per lane
#pragma unroll
  for (int i = 0; i < ITER; ++i) {
    int off16 = i * 64 + lane;
    int lrow = (off16 * 8) / COUT;  // 8 ushorts per uint4
    if (rbase + lrow < NN) gdst[off16] = *(const uint4*)&ob[off16 * 8];
  }
}

// ---------------- gather (bf16 rows), layers 1/2: fused relu+bias+scale ----
// An[i] = bf16(relu(dinv[i]*(T[i]+sum T[col])+b)). T,An: bf16 [NNP][128].
__global__ __launch_bounds__(256) void k_gather12(const int* __restrict__ row_ptr,
                                                  const int* __restrict__ col,
                                                  const uint* __restrict__ T,
                                                  const float* __restrict__ dinv,
                                                  const float* __restrict__ bias,
                                                  uint* __restrict__ An) {
  int w = (blockIdx.x * 256 + threadIdx.x) >> 6;
  int lane = threadIdx.x & 63;
  if (w >= NN) return;
  int s = row_ptr[w], t = row_ptr[w + 1];
  const int h = lane >> 5, cl = lane & 31;  // uint2 covers channels 4cl..4cl+3
  float a0 = 0.f, a1 = 0.f, a2 = 0.f, a3 = 0.f;
  if (h == 0) {
    uint2 u = *(const uint2*)&T[(size_t)w * 64 + cl * 2];
    a0 = __uint_as_float(u.x << 16);
    a1 = __uint_as_float(u.x & 0xffff0000u);
    a2 = __uint_as_float(u.y << 16);
    a3 = __uint_as_float(u.y & 0xffff0000u);
  }
  int e = s + h;
  for (; e + 6 < t; e += 8) {
    int c0 = col[e], c1 = col[e + 2], c2 = col[e + 4], c3 = col[e + 6];
    uint2 v0 = *(const uint2*)&T[(size_t)c0 * 64 + cl * 2];
    uint2 v1 = *(const uint2*)&T[(size_t)c1 * 64 + cl * 2];
    uint2 v2 = *(const uint2*)&T[(size_t)c2 * 64 + cl * 2];
    uint2 v3 = *(const uint2*)&T[(size_t)c3 * 64 + cl * 2];
    a0 += __uint_as_float(v0.x << 16) + __uint_as_float(v1.x << 16) +
          __uint_as_float(v2.x << 16) + __uint_as_float(v3.x << 16);
    a1 += __uint_as_float(v0.x & 0xffff0000u) + __uint_as_float(v1.x & 0xffff0000u) +
          __uint_as_float(v2.x & 0xffff0000u) + __uint_as_float(v3.x & 0xffff0000u);
    a2 += __uint_as_float(v0.y << 16) + __uint_as_float(v1.y << 16) +
          __uint_as_float(v2.y << 16) + __uint_as_float(v3.y << 16);
    a3 += __uint_as_float(v0.y & 0xffff0000u) + __uint_as_float(v1.y & 0xffff0000u) +
          __uint_as_float(v2.y & 0xffff0000u) + __uint_as_float(v3.y & 0xffff0000u);
  }
  for (; e < t; e += 2) {
    uint2 v = *(const uint2*)&T[(size_t)col[e] * 64 + cl * 2];
    a0 += __uint_as_float(v.x << 16);
    a1 += __uint_as_float(v.x & 0xffff0000u);
    a2 += __uint_as_float(v.y << 16);
    a3 += __uint_as_float(v.y & 0xffff0000u);
  }
  a0 += __shfl_down(a0, 32, 64);
  a1 += __shfl_down(a1, 32, 64);
  a2 += __shfl_down(a2, 32, 64);
  a3 += __shfl_down(a3, 32, 64);
  if (h == 0) {
    float4 b = *(const float4*)&bias[cl * 4];
    float dv = dinv[w];
    float r0 = fmaxf(fmaf(dv, a0, b.x), 0.f);
    float r1 = fmaxf(fmaf(dv, a1, b.y), 0.f);
    float r2 = fmaxf(fmaf(dv, a2, b.z), 0.f);
    float r3 = fmaxf(fmaf(dv, a3, b.w), 0.f);
    uint2 o;
    o.x = (uint)f2bf(r0) | ((uint)f2bf(r1) << 16);
    o.y = (uint)f2bf(r2) | ((uint)f2bf(r3) << 16);
    *(uint2*)&An[(size_t)w * 64 + cl * 2] = o;
  }
}

// ---------------- gather layer 3: bf16 in, raw fp32 out (64 ch) ----------
__global__ __launch_bounds__(256) void k_gather3(const int* __restrict__ row_ptr,
                                                 const int* __restrict__ col,
                                                 const uint* __restrict__ T,
                                                 float* __restrict__ G3) {
  int w = (blockIdx.x * 256 + threadIdx.x) >> 6;
  int lane = threadIdx.x & 63;
  if (w >= NN) return;
  int s = row_ptr[w], t = row_ptr[w + 1];
  const int q = lane >> 4, cl = lane & 15;
  float a0 = 0.f, a1 = 0.f, a2 = 0.f, a3 = 0.f;
  if (q == 0) {
    uint2 u = *(const uint2*)&T[(size_t)w * 32 + cl * 2];
    a0 = __uint_as_float(u.x << 16);
    a1 = __uint_as_float(u.x & 0xffff0000u);
    a2 = __uint_as_float(u.y << 16);
    a3 = __uint_as_float(u.y & 0xffff0000u);
  }
  int e = s + q;
  for (; e + 4 < t; e += 8) {
    int c0 = col[e], c1 = col[e + 4];
    uint2 v0 = *(const uint2*)&T[(size_t)c0 * 32 + cl * 2];
    uint2 v1 = *(const uint2*)&T[(size_t)c1 * 32 + cl * 2];
    a0 += __uint_as_float(v0.x << 16) + __uint_as_float(v1.x << 16);
    a1 += __uint_as_float(v0.x & 0xffff0000u) + __uint_as_float(v1.x & 0xffff0000u);
    a2 += __uint_as_float(v0.y << 16) + __uint_as_float(v1.y << 16);
    a3 += __uint_as_float(v0.y & 0xffff0000u) + __uint_as_float(v1.y & 0xffff0000u);
  }
  for (; e < t; e += 4) {
    uint2 v = *(const uint2*)&T[(size_t)col[e] * 32 + cl * 2];
    a0 += __uint_as_float(v.x << 16);
    a1 += __uint_as_float(v.x & 0xffff0000u);
    a2 += __uint_as_float(v.y << 16);
    a3 += __uint_as_float(v.y & 0xffff0000u);
  }
  a0 += __shfl_down(a0, 16, 64);
  a1 += __shfl_down(a1, 16, 64);
  a2 += __shfl_down(a2, 16, 64);
  a3 += __shfl_down(a3, 16, 64);
  a0 += __shfl_down(a0, 32, 64);
  a1 += __shfl_down(a1, 32, 64);
  a2 += __shfl_down(a2, 32, 64);
  a3 += __shfl_down(a3, 32, 64);
  if (q == 0) *(float4*)&G3[(size_t)w * 64 + cl * 4] = make_float4(a0, a1, a2, a3);
}

// ---------------- pair decode ----------------
__global__ __launch_bounds__(256) void k_decode(const int* __restrict__ ni,
                                                const int* __restrict__ nj,
                                                const float* __restrict__ G3,
                                                const float* __restrict__ dinv,
                                                const float* __restrict__ b3,
                                                float* __restrict__ out) {
  int p = blockIdx.x * 4 + (threadIdx.x >> 6);
  int lane = threadIdx.x & 63;
  if (p >= NP) return;
  int i = ni[p], j = nj[p];
  float hi = fmaf(dinv[i], G3[(size_t)i * 64 + lane], b3[lane]);
  float hj = fmaf(dinv[j], G3[(size_t)j * 64 + lane], b3[lane]);
  float v = hi * hj;
#pragma unroll
  for (int off = 32; off > 0; off >>= 1) v += __shfl_down(v, off, 64);
  if (lane == 0) out[p] = v;
}

extern "C" void kernel_launch(void* const* d_in, const int* in_sizes, int n_in,
                              void* d_out, int out_size, void* d_ws, size_t ws_size,
                              hipStream_t stream) {
  const float* x  = (const float*)d_in[0];
  const int*   ei = (const int*)d_in[1];
  const int*   ni = (const int*)d_in[2];
  const int*   nj = (const int*)d_in[3];
  const float* W1 = (const float*)d_in[4];
  const float* b1 = (const float*)d_in[5];
  const float* W2 = (const float*)d_in[6];
  const float* b2 = (const float*)d_in[7];
  const float* W3 = (const float*)d_in[8];
  const float* b3 = (const float*)d_in[9];
  float* out = (float*)d_out;

  // ws carve (4-byte words; all sections multiple of 64 words -> aligned)
  float* dinv    = (float*)d_ws;              // 102400
  int*   cnt     = (int*)(dinv + 102400);     // 102400
  int*   row_ptr = cnt + 102400;              // 102400 (NN+1 used)
  int*   bsum    = row_ptr + 102400;          // 256
  int*   gcur    = bsum + 256;                // 1024
  int*   col     = gcur + 1024;               // NE
  uint*  Wt1     = (uint*)(col + NE);         // 8192
  uint*  Wt2     = Wt1 + 8192;                // 8192
  uint*  Wt3     = Wt2 + 8192;                // 4096
  uint*  Tbf     = Wt3 + 4096;                // NNP*64 (bf16 [NNP][128])
  uint*  Abf     = Tbf + (size_t)NNP * 64;    // NNP*64
  float* G3      = (float*)(Abf + (size_t)NNP * 64);  // NNP*64 fp32
  int*   aux     = (int*)G3;  // 12.6 MB arena, dead before gather3 writes G3

  // ---- CSR build + dinv ----
  k_init_gcur<<<4, 256, 0, stream>>>(gcur);
  k_bucket<<<(NE + BKB - 1) / BKB, 256, 0, stream>>>(ei, gcur, aux);
  k_bktcount<<<NBKT, 256, 0, stream>>>(gcur, aux, cnt);
  k_part_sum<<<NBLK, SCANB, 0, stream>>>(cnt, bsum);
  k_scan_bsum<<<1, 256, 0, stream>>>(bsum);
  k_scan_final<<<NBLK, SCANB, 0, stream>>>(cnt, bsum, row_ptr, dinv);
  k_bktsort<<<NBKT, 256, 0, stream>>>(gcur, aux, row_ptr, col);

  // ---- weight pre-pack ----
  k_prepw<8><<<8, 256, 0, stream>>>(W1, Wt1);
  k_prepw<8><<<8, 256, 0, stream>>>(W2, Wt2);
  k_prepw<4><<<4, 256, 0, stream>>>(W3, Wt3);

  const int GB = NNP / 64;                 // 1563
  const int GATB = (NN * 64 + 255) / 256;  // 25000

  // layer 1 (x fp32 -> Tbf bf16)
  k_gemm_mfma<128, true><<<GB, 256, 0, stream>>>(x, Wt1, dinv, (unsigned short*)Tbf);
  k_gather12<<<GATB, 256, 0, stream>>>(row_ptr, col, Tbf, dinv, b1, Abf);
  // layer 2
  k_gemm_mfma<128, false><<<GB, 256, 0, stream>>>(Abf, Wt2, dinv, (unsigned short*)Tbf);
  k_gather12<<<GATB, 256, 0, stream>>>(row_ptr, col, Tbf, dinv, b2, Abf);
  // layer 3 (COUT=64)
  k_gemm_mfma<64, false><<<GB, 256, 0, stream>>>(Abf, Wt3, dinv, (unsigned short*)Tbf);
  k_gather3<<<GATB, 256, 0, stream>>>(row_ptr, col, Tbf, G3);
  // decode
  k_decode<<<NP / 4, 256, 0, stream>>>(ni, nj, G3, dinv, b3, out);
}

// Round 6
// 358.872 us; speedup vs baseline: 19.8875x; 1.1185x over previous
//
#include <hip/hip_runtime.h>

#define NN 100000
#define NNP 100032   // padded to 1563*64 rows so GEMM tiles never go OOB in ws
#define NE 1600000
#define NP 200000
#define NBKT 782     // buckets of 128 nodes
#define BCAP 3072    // per-bucket arena capacity (mean 2046)
#define BKB 4096     // edges per k_bucket block

typedef short s16x8 __attribute__((ext_vector_type(8)));
typedef float f32x4 __attribute__((ext_vector_type(4)));

__device__ __forceinline__ unsigned short f2bf(float f) {  // RNE fp32->bf16
  unsigned int u = __float_as_uint(f);
  u += 0x7fffu + ((u >> 16) & 1u);
  return (unsigned short)(u >> 16);
}

__device__ __forceinline__ void upadd(uint u, float& lo, float& hi) {
  lo += __uint_as_float(u << 16);
  hi += __uint_as_float(u & 0xffff0000u);
}

// ---------------- bucket-sort phase A (unchanged) ----------------
__global__ __launch_bounds__(256) void k_init_gcur(int* gcur) {
  int i = blockIdx.x * 256 + threadIdx.x;
  if (i < 1024) gcur[i] = i * BCAP;
}

__global__ __launch_bounds__(256) void k_bucket(const int* __restrict__ ei,
                                                int* __restrict__ gcur,
                                                int* __restrict__ aux) {
  __shared__ int cnt[1024];
  __shared__ int scn[1024];
  __shared__ int cur[1024];
  __shared__ int sc[256];
  __shared__ int sorted[BKB];
  __shared__ unsigned short sbkt[BKB];
  const int t = threadIdx.x;
  const int base = blockIdx.x * BKB;

  for (int i = t; i < 1024; i += 256) cnt[i] = 0;
  __syncthreads();

  int pk[16], bk[16];
#pragma unroll
  for (int i = 0; i < 16; ++i) {
    int e = base + t + 256 * i;
    if (e < NE) {
      int src = ei[e], dst = ei[NE + e];
      bk[i] = dst >> 7;
      pk[i] = src | ((dst & 127) << 17);
      atomicAdd(&cnt[bk[i]], 1);
    } else {
      bk[i] = -1;
    }
  }
  __syncthreads();

  int s0 = cnt[4 * t], s1 = cnt[4 * t + 1], s2 = cnt[4 * t + 2], s3 = cnt[4 * t + 3];
  int local = s0 + s1 + s2 + s3;
  sc[t] = local;
  __syncthreads();
  for (int off = 1; off < 256; off <<= 1) {
    int a = (t >= off) ? sc[t - off] : 0;
    __syncthreads();
    sc[t] += a;
    __syncthreads();
  }
  int b0 = sc[t] - local;
  scn[4 * t] = b0;
  scn[4 * t + 1] = b0 + s0;
  scn[4 * t + 2] = b0 + s0 + s1;
  scn[4 * t + 3] = b0 + s0 + s1 + s2;
  cur[4 * t] = scn[4 * t];
  cur[4 * t + 1] = scn[4 * t + 1];
  cur[4 * t + 2] = scn[4 * t + 2];
  cur[4 * t + 3] = scn[4 * t + 3];
  __syncthreads();
  const int tot = sc[255];

#pragma unroll
  for (int i = 0; i < 16; ++i) {
    if (bk[i] >= 0) {
      int pos = atomicAdd(&cur[bk[i]], 1);
      sorted[pos] = pk[i];
      sbkt[pos] = (unsigned short)bk[i];
    }
  }
  __syncthreads();

  for (int b = t; b < 1024; b += 256) {
    int c = cnt[b];
    if (c > 0) cur[b] = atomicAdd(&gcur[b], c);
  }
  __syncthreads();

  for (int k = t; k < tot; k += 256) {
    int b = sbkt[k];
    aux[cur[b] + (k - scn[b])] = sorted[k];
  }
}

// ---------------- merged CSR finalize: count+scan+row_ptr+dinv+sort ---------
// Bucket totals are implicit: total[b] = gcur[b] - b*BCAP. Each block computes
// its global base via a strided reduction over buckets < b, then LDS-scans its
// 128 local degree counts, writes row_ptr/dinv, and scatters col.
__global__ __launch_bounds__(256) void k_csr(const int* __restrict__ gcur,
                                             const int* __restrict__ aux,
                                             int* __restrict__ row_ptr,
                                             float* __restrict__ dinv,
                                             int* __restrict__ col) {
  __shared__ int red[256];
  __shared__ int c[128];
  __shared__ int cur[128];
  const int b = blockIdx.x, t = threadIdx.x;
  int p = 0;
  for (int i = t; i < b; i += 256) p += gcur[i] - i * BCAP;  // <=4 iters
  red[t] = p;
  if (t < 128) c[t] = 0;
  __syncthreads();
  for (int off = 128; off > 0; off >>= 1) {
    if (t < off) red[t] += red[t + off];
    __syncthreads();
  }
  const int base = red[0];
  const int m = gcur[b] - b * BCAP;
  const int* a = aux + (size_t)b * BCAP;
  __syncthreads();  // red reuse below
  for (int k = t; k < m; k += 256) atomicAdd(&c[a[k] >> 17], 1);
  __syncthreads();
  int val = (t < 128) ? c[t] : 0;
  red[t] = val;
  __syncthreads();
  for (int off = 1; off < 128; off <<= 1) {
    int add = (t >= off && t < 128) ? red[t - off] : 0;
    __syncthreads();
    if (t < 128) red[t] += add;
    __syncthreads();
  }
  if (t < 128) {
    int excl = red[t] - val + base;
    int node = b * 128 + t;
    if (node < NN) {
      row_ptr[node] = excl;
      dinv[node] = rsqrtf((float)(val + 1));
      cur[t] = excl;
    }
  }
  if (b == NBKT - 1 && t == 0) row_ptr[NN] = base + m;
  __syncthreads();
  for (int k = t; k < m; k += 256) {
    int pk2 = a[k];
    int pos = atomicAdd(&cur[pk2 >> 17], 1);
    col[pos] = pk2 & 0x1FFFF;
  }
}

// ---------------- W pre-pack (unchanged) ----------------
template <int NT>
__global__ __launch_bounds__(256) void k_prepw(const float* __restrict__ W,
                                               uint* __restrict__ Wt) {
  constexpr int COUT = NT * 16;
  int tid = blockIdx.x * 256 + threadIdx.x;
  if (tid >= 4 * NT * 64) return;
  int lane = tid & 63, comb = tid >> 6;
  int ks = comb / NT, tl = comb % NT;
  int q = lane >> 4, n = lane & 15;
  uint w[4];
#pragma unroll
  for (int jj = 0; jj < 4; ++jj) {
    int k0 = ks * 32 + q * 8 + 2 * jj;
    uint lo = f2bf(W[k0 * COUT + tl * 16 + n]);
    uint hi = f2bf(W[(k0 + 1) * COUT + tl * 16 + n]);
    w[jj] = lo | (hi << 16);
  }
  uint4* dst = (uint4*)Wt;
  dst[comb * 64 + lane] = make_uint4(w[0], w[1], w[2], w[3]);
}

// ---------------- MFMA GEMM (unchanged from R5) ----------------
template <int COUT, bool AFP32>
__global__ __launch_bounds__(256) void k_gemm_mfma(const void* __restrict__ Av,
                                                   const uint* __restrict__ Wt,
                                                   const float* __restrict__ dinv,
                                                   unsigned short* __restrict__ T) {
  constexpr int NT = COUT / 16;
  __shared__ __align__(16) uint Wlds[4 * NT * 64 * 4];
  __shared__ __align__(16) unsigned short Obuf[64 * COUT];
  const int t = threadIdx.x;
  {
    const uint4* src = (const uint4*)Wt;
    uint4* dst = (uint4*)Wlds;
    for (int i = t; i < 4 * NT * 64; i += 256) dst[i] = src[i];
  }
  __syncthreads();

  const int wv = t >> 6, lane = t & 63;
  const int n = lane & 15, quad = lane >> 4;
  const int rbase = blockIdx.x * 64 + wv * 16;

  union AB { uint4 u; s16x8 s; };
  AB a[4];
  if constexpr (AFP32) {
    const float* A = (const float*)Av;
    int row = rbase + n;
    if (row >= NN) row = NN - 1;
    const float* ap = A + (size_t)row * 128;
#pragma unroll
    for (int ks = 0; ks < 4; ++ks) {
      float4 v0 = *(const float4*)(ap + ks * 32 + quad * 8);
      float4 v1 = *(const float4*)(ap + ks * 32 + quad * 8 + 4);
      a[ks].u.x = (uint)f2bf(v0.x) | ((uint)f2bf(v0.y) << 16);
      a[ks].u.y = (uint)f2bf(v0.z) | ((uint)f2bf(v0.w) << 16);
      a[ks].u.z = (uint)f2bf(v1.x) | ((uint)f2bf(v1.y) << 16);
      a[ks].u.w = (uint)f2bf(v1.z) | ((uint)f2bf(v1.w) << 16);
    }
  } else {
    const uint4* A = (const uint4*)Av;
    int row = rbase + n;
#pragma unroll
    for (int ks = 0; ks < 4; ++ks) a[ks].u = A[(size_t)row * 16 + ks * 4 + quad];
  }

  f32x4 acc[NT];
#pragma unroll
  for (int tl = 0; tl < NT; ++tl) acc[tl] = (f32x4){0.f, 0.f, 0.f, 0.f};

#pragma unroll
  for (int ks = 0; ks < 4; ++ks) {
#pragma unroll
    for (int tl = 0; tl < NT; ++tl) {
      AB b;
      b.u = *(const uint4*)&Wlds[((ks * NT + tl) * 64 + lane) * 4];
      acc[tl] = __builtin_amdgcn_mfma_f32_16x16x32_bf16(a[ks].s, b.s, acc[tl], 0, 0, 0);
    }
  }

  float4 dv = *(const float4*)(dinv + rbase + quad * 4);
  float dvv[4] = {dv.x, dv.y, dv.z, dv.w};
  unsigned short* ob = Obuf + wv * 16 * COUT;
#pragma unroll
  for (int tl = 0; tl < NT; ++tl)
#pragma unroll
    for (int r = 0; r < 4; ++r)
      ob[(quad * 4 + r) * COUT + tl * 16 + n] = f2bf(acc[tl][r] * dvv[r]);

  uint4* gdst = (uint4*)(T + (size_t)rbase * COUT);
  constexpr int ITER = COUT / 32;
#pragma unroll
  for (int i = 0; i < ITER; ++i) {
    int off16 = i * 64 + lane;
    int lrow = (off16 * 8) / COUT;
    if (rbase + lrow < NN) gdst[off16] = *(const uint4*)&ob[off16 * 8];
  }
}

// ---------------- gather layers 1/2: quarter-wave uint4, 16 rows in flight --
// An[i] = bf16(relu(dinv[i]*(T[i]+sum T[col])+b)). T,An: bf16 [NNP][128].
__global__ __launch_bounds__(256) void k_gather12(const int* __restrict__ row_ptr,
                                                  const int* __restrict__ col,
                                                  const uint4* __restrict__ T4,
                                                  const float* __restrict__ dinv,
                                                  const float* __restrict__ bias,
                                                  uint4* __restrict__ An) {
  int w = (blockIdx.x * 256 + threadIdx.x) >> 6;
  int lane = threadIdx.x & 63;
  if (w >= NN) return;
  int s = row_ptr[w], tend = row_ptr[w + 1];
  const int q = lane >> 4;   // edge group 0..3
  const int cl = lane & 15;  // uint4 (8 channels) within 256B row
  float acc[8] = {0.f, 0.f, 0.f, 0.f, 0.f, 0.f, 0.f, 0.f};
  if (q == 0) {
    uint4 u = T4[(size_t)w * 16 + cl];  // self-loop term
    upadd(u.x, acc[0], acc[1]);
    upadd(u.y, acc[2], acc[3]);
    upadd(u.z, acc[4], acc[5]);
    upadd(u.w, acc[6], acc[7]);
  }
  int e = s + q;
  for (; e + 12 < tend; e += 16) {  // 4 edges per group per iter
    int c0 = col[e], c1 = col[e + 4], c2 = col[e + 8], c3 = col[e + 12];
    uint4 v0 = T4[(size_t)c0 * 16 + cl];
    uint4 v1 = T4[(size_t)c1 * 16 + cl];
    uint4 v2 = T4[(size_t)c2 * 16 + cl];
    uint4 v3 = T4[(size_t)c3 * 16 + cl];
    upadd(v0.x, acc[0], acc[1]); upadd(v0.y, acc[2], acc[3]);
    upadd(v0.z, acc[4], acc[5]); upadd(v0.w, acc[6], acc[7]);
    upadd(v1.x, acc[0], acc[1]); upadd(v1.y, acc[2], acc[3]);
    upadd(v1.z, acc[4], acc[5]); upadd(v1.w, acc[6], acc[7]);
    upadd(v2.x, acc[0], acc[1]); upadd(v2.y, acc[2], acc[3]);
    upadd(v2.z, acc[4], acc[5]); upadd(v2.w, acc[6], acc[7]);
    upadd(v3.x, acc[0], acc[1]); upadd(v3.y, acc[2], acc[3]);
    upadd(v3.z, acc[4], acc[5]); upadd(v3.w, acc[6], acc[7]);
  }
  for (; e < tend; e += 4) {
    uint4 v = T4[(size_t)col[e] * 16 + cl];
    upadd(v.x, acc[0], acc[1]); upadd(v.y, acc[2], acc[3]);
    upadd(v.z, acc[4], acc[5]); upadd(v.w, acc[6], acc[7]);
  }
#pragma unroll
  for (int i = 0; i < 8; ++i) {
    acc[i] += __shfl_down(acc[i], 16, 64);
    acc[i] += __shfl_down(acc[i], 32, 64);
  }
  if (q == 0) {
    float4 b0 = *(const float4*)&bias[cl * 8];
    float4 b1 = *(const float4*)&bias[cl * 8 + 4];
    float dv = dinv[w];
    float r[8];
    r[0] = fmaxf(fmaf(dv, acc[0], b0.x), 0.f);
    r[1] = fmaxf(fmaf(dv, acc[1], b0.y), 0.f);
    r[2] = fmaxf(fmaf(dv, acc[2], b0.z), 0.f);
    r[3] = fmaxf(fmaf(dv, acc[3], b0.w), 0.f);
    r[4] = fmaxf(fmaf(dv, acc[4], b1.x), 0.f);
    r[5] = fmaxf(fmaf(dv, acc[5], b1.y), 0.f);
    r[6] = fmaxf(fmaf(dv, acc[6], b1.z), 0.f);
    r[7] = fmaxf(fmaf(dv, acc[7], b1.w), 0.f);
    uint4 o;
    o.x = (uint)f2bf(r[0]) | ((uint)f2bf(r[1]) << 16);
    o.y = (uint)f2bf(r[2]) | ((uint)f2bf(r[3]) << 16);
    o.z = (uint)f2bf(r[4]) | ((uint)f2bf(r[5]) << 16);
    o.w = (uint)f2bf(r[6]) | ((uint)f2bf(r[7]) << 16);
    An[(size_t)w * 16 + cl] = o;
  }
}

// ---------------- gather layer 3: eighth-wave uint4, fp32 out -------------
__global__ __launch_bounds__(256) void k_gather3(const int* __restrict__ row_ptr,
                                                 const int* __restrict__ col,
                                                 const uint4* __restrict__ T4,
                                                 float* __restrict__ G3) {
  int w = (blockIdx.x * 256 + threadIdx.x) >> 6;
  int lane = threadIdx.x & 63;
  if (w >= NN) return;
  int s = row_ptr[w], tend = row_ptr[w + 1];
  const int g = lane >> 3;  // edge group 0..7
  const int cl = lane & 7;  // uint4 (8 channels) within 128B row
  float acc[8] = {0.f, 0.f, 0.f, 0.f, 0.f, 0.f, 0.f, 0.f};
  if (g == 0) {
    uint4 u = T4[(size_t)w * 8 + cl];
    upadd(u.x, acc[0], acc[1]);
    upadd(u.y, acc[2], acc[3]);
    upadd(u.z, acc[4], acc[5]);
    upadd(u.w, acc[6], acc[7]);
  }
  int e = s + g;
  for (; e + 8 < tend; e += 16) {  // 2 edges per group per iter
    int c0 = col[e], c1 = col[e + 8];
    uint4 v0 = T4[(size_t)c0 * 8 + cl];
    uint4 v1 = T4[(size_t)c1 * 8 + cl];
    upadd(v0.x, acc[0], acc[1]); upadd(v0.y, acc[2], acc[3]);
    upadd(v0.z, acc[4], acc[5]); upadd(v0.w, acc[6], acc[7]);
    upadd(v1.x, acc[0], acc[1]); upadd(v1.y, acc[2], acc[3]);
    upadd(v1.z, acc[4], acc[5]); upadd(v1.w, acc[6], acc[7]);
  }
  for (; e < tend; e += 8) {
    uint4 v = T4[(size_t)col[e] * 8 + cl];
    upadd(v.x, acc[0], acc[1]); upadd(v.y, acc[2], acc[3]);
    upadd(v.z, acc[4], acc[5]); upadd(v.w, acc[6], acc[7]);
  }
#pragma unroll
  for (int i = 0; i < 8; ++i) {
    acc[i] += __shfl_down(acc[i], 8, 64);
    acc[i] += __shfl_down(acc[i], 16, 64);
    acc[i] += __shfl_down(acc[i], 32, 64);
  }
  if (g == 0) {
    float* gp = &G3[(size_t)w * 64 + cl * 8];
    *(float4*)gp = make_float4(acc[0], acc[1], acc[2], acc[3]);
    *(float4*)(gp + 4) = make_float4(acc[4], acc[5], acc[6], acc[7]);
  }
}

// ---------------- pair decode: 4 pairs/wave (quarter-wave float4) ---------
__global__ __launch_bounds__(256) void k_decode(const int* __restrict__ ni,
                                                const int* __restrict__ nj,
                                                const float* __restrict__ G3,
                                                const float* __restrict__ dinv,
                                                const float* __restrict__ b3,
                                                float* __restrict__ out) {
  int p = blockIdx.x * 16 + (threadIdx.x >> 4);
  int cl = threadIdx.x & 15;
  int i = ni[p], j = nj[p];
  float4 gi = *(const float4*)&G3[(size_t)i * 64 + cl * 4];
  float4 gj = *(const float4*)&G3[(size_t)j * 64 + cl * 4];
  float4 bb = *(const float4*)&b3[cl * 4];
  float di = dinv[i], dj = dinv[j];
  float v = fmaf(di, gi.x, bb.x) * fmaf(dj, gj.x, bb.x) +
            fmaf(di, gi.y, bb.y) * fmaf(dj, gj.y, bb.y) +
            fmaf(di, gi.z, bb.z) * fmaf(dj, gj.z, bb.z) +
            fmaf(di, gi.w, bb.w) * fmaf(dj, gj.w, bb.w);
  v += __shfl_xor(v, 1, 64);
  v += __shfl_xor(v, 2, 64);
  v += __shfl_xor(v, 4, 64);
  v += __shfl_xor(v, 8, 64);
  if (cl == 0) out[p] = v;
}

extern "C" void kernel_launch(void* const* d_in, const int* in_sizes, int n_in,
                              void* d_out, int out_size, void* d_ws, size_t ws_size,
                              hipStream_t stream) {
  const float* x  = (const float*)d_in[0];
  const int*   ei = (const int*)d_in[1];
  const int*   ni = (const int*)d_in[2];
  const int*   nj = (const int*)d_in[3];
  const float* W1 = (const float*)d_in[4];
  const float* b1 = (const float*)d_in[5];
  const float* W2 = (const float*)d_in[6];
  const float* b2 = (const float*)d_in[7];
  const float* W3 = (const float*)d_in[8];
  const float* b3 = (const float*)d_in[9];
  float* out = (float*)d_out;

  // ws carve (4-byte words)
  float* dinv    = (float*)d_ws;              // 102400
  int*   row_ptr = (int*)(dinv + 102400);     // 102400 (NN+1 used)
  int*   gcur    = row_ptr + 102400;          // 1024
  int*   col     = gcur + 1024;               // NE
  uint*  Wt1     = (uint*)(col + NE);         // 8192
  uint*  Wt2     = Wt1 + 8192;                // 8192
  uint*  Wt3     = Wt2 + 8192;                // 4096
  uint*  Tbf     = Wt3 + 4096;                // NNP*64 (bf16 [NNP][128])
  uint*  Abf     = Tbf + (size_t)NNP * 64;    // NNP*64
  float* G3      = (float*)(Abf + (size_t)NNP * 64);  // NNP*64 fp32
  int*   aux     = (int*)G3;  // 12.6 MB arena, dead before gather3 writes G3

  // ---- CSR build + dinv ----
  k_init_gcur<<<4, 256, 0, stream>>>(gcur);
  k_bucket<<<(NE + BKB - 1) / BKB, 256, 0, stream>>>(ei, gcur, aux);
  k_csr<<<NBKT, 256, 0, stream>>>(gcur, aux, row_ptr, dinv, col);

  // ---- weight pre-pack ----
  k_prepw<8><<<8, 256, 0, stream>>>(W1, Wt1);
  k_prepw<8><<<8, 256, 0, stream>>>(W2, Wt2);
  k_prepw<4><<<4, 256, 0, stream>>>(W3, Wt3);

  const int GB = NNP / 64;                 // 1563
  const int GATB = (NN * 64 + 255) / 256;  // 25000

  // layer 1 (x fp32 -> Tbf bf16)
  k_gemm_mfma<128, true><<<GB, 256, 0, stream>>>(x, Wt1, dinv, (unsigned short*)Tbf);
  k_gather12<<<GATB, 256, 0, stream>>>(row_ptr, col, (const uint4*)Tbf, dinv, b1, (uint4*)Abf);
  // layer 2
  k_gemm_mfma<128, false><<<GB, 256, 0, stream>>>(Abf, Wt2, dinv, (unsigned short*)Tbf);
  k_gather12<<<GATB, 256, 0, stream>>>(row_ptr, col, (const uint4*)Tbf, dinv, b2, (uint4*)Abf);
  // layer 3 (COUT=64)
  k_gemm_mfma<64, false><<<GB, 256, 0, stream>>>(Abf, Wt3, dinv, (unsigned short*)Tbf);
  k_gather3<<<GATB, 256, 0, stream>>>(row_ptr, col, (const uint4*)Tbf, G3);
  // decode
  k_decode<<<NP / 16, 256, 0, stream>>>(ni, nj, G3, dinv, b3, out);
}

// Round 7
// 344.967 us; speedup vs baseline: 20.6891x; 1.0403x over previous
//
#include <hip/hip_runtime.h>

#define NN 100000
#define NNP 100032   // padded to 1563*64 rows; rows NN..NNP-1 are written as zeros
#define NE 1600000
#define NP 200000
#define NBKT 782     // buckets of 128 nodes
#define BCAP 3072    // per-bucket arena capacity (mean 2046)
#define BKB 4096     // edges per k_bucket block

typedef short s16x8 __attribute__((ext_vector_type(8)));
typedef float f32x4 __attribute__((ext_vector_type(4)));

__device__ __forceinline__ unsigned short f2bf(float f) {  // RNE fp32->bf16
  unsigned int u = __float_as_uint(f);
  u += 0x7fffu + ((u >> 16) & 1u);
  return (unsigned short)(u >> 16);
}

__device__ __forceinline__ void upadd(uint u, float& lo, float& hi) {
  lo += __uint_as_float(u << 16);
  hi += __uint_as_float(u & 0xffff0000u);
}

// ---------------- setup: gcur init + W pre-pack, one launch ----------------
template <int NT>
__device__ __forceinline__ void prepw_dev(const float* __restrict__ W,
                                          uint* __restrict__ Wt, int tid) {
  constexpr int COUT = NT * 16;
  if (tid >= 4 * NT * 64) return;
  int lane = tid & 63, comb = tid >> 6;
  int ks = comb / NT, tl = comb % NT;
  int q = lane >> 4, n = lane & 15;
  uint w[4];
#pragma unroll
  for (int jj = 0; jj < 4; ++jj) {
    int k0 = ks * 32 + q * 8 + 2 * jj;
    uint lo = f2bf(W[k0 * COUT + tl * 16 + n]);
    uint hi = f2bf(W[(k0 + 1) * COUT + tl * 16 + n]);
    w[jj] = lo | (hi << 16);
  }
  ((uint4*)Wt)[comb * 64 + lane] = make_uint4(w[0], w[1], w[2], w[3]);
}

__global__ __launch_bounds__(256) void k_setup(const float* __restrict__ W1,
                                               const float* __restrict__ W2,
                                               const float* __restrict__ W3,
                                               uint* __restrict__ Wt1,
                                               uint* __restrict__ Wt2,
                                               uint* __restrict__ Wt3,
                                               int* __restrict__ gcur) {
  int b = blockIdx.x, t = threadIdx.x;
  if (b < 4) {
    int i = b * 256 + t;
    if (i < 1024) gcur[i] = i * BCAP;
  } else if (b < 12) {
    prepw_dev<8>(W1, Wt1, (b - 4) * 256 + t);
  } else if (b < 20) {
    prepw_dev<8>(W2, Wt2, (b - 12) * 256 + t);
  } else {
    prepw_dev<4>(W3, Wt3, (b - 20) * 256 + t);
  }
}

// ---------------- bucket-sort phase A ----------------
__global__ __launch_bounds__(256) void k_bucket(const int* __restrict__ ei,
                                                int* __restrict__ gcur,
                                                int* __restrict__ aux) {
  __shared__ int cnt[1024];
  __shared__ int scn[1024];
  __shared__ int cur[1024];
  __shared__ int sc[256];
  __shared__ int sorted[BKB];
  __shared__ unsigned short sbkt[BKB];
  const int t = threadIdx.x;
  const int base = blockIdx.x * BKB;

  for (int i = t; i < 1024; i += 256) cnt[i] = 0;
  __syncthreads();

  int pk[16], bk[16];
#pragma unroll
  for (int i = 0; i < 16; ++i) {
    int e = base + t + 256 * i;
    if (e < NE) {
      int src = ei[e], dst = ei[NE + e];
      bk[i] = dst >> 7;
      pk[i] = src | ((dst & 127) << 17);
      atomicAdd(&cnt[bk[i]], 1);
    } else {
      bk[i] = -1;
    }
  }
  __syncthreads();

  int s0 = cnt[4 * t], s1 = cnt[4 * t + 1], s2 = cnt[4 * t + 2], s3 = cnt[4 * t + 3];
  int local = s0 + s1 + s2 + s3;
  sc[t] = local;
  __syncthreads();
  for (int off = 1; off < 256; off <<= 1) {
    int a = (t >= off) ? sc[t - off] : 0;
    __syncthreads();
    sc[t] += a;
    __syncthreads();
  }
  int b0 = sc[t] - local;
  scn[4 * t] = b0;
  scn[4 * t + 1] = b0 + s0;
  scn[4 * t + 2] = b0 + s0 + s1;
  scn[4 * t + 3] = b0 + s0 + s1 + s2;
  cur[4 * t] = scn[4 * t];
  cur[4 * t + 1] = scn[4 * t + 1];
  cur[4 * t + 2] = scn[4 * t + 2];
  cur[4 * t + 3] = scn[4 * t + 3];
  __syncthreads();
  const int tot = sc[255];

#pragma unroll
  for (int i = 0; i < 16; ++i) {
    if (bk[i] >= 0) {
      int pos = atomicAdd(&cur[bk[i]], 1);
      sorted[pos] = pk[i];
      sbkt[pos] = (unsigned short)bk[i];
    }
  }
  __syncthreads();

  for (int b = t; b < 1024; b += 256) {
    int c = cnt[b];
    if (c > 0) cur[b] = atomicAdd(&gcur[b], c);
  }
  __syncthreads();

  for (int k = t; k < tot; k += 256) {
    int b = sbkt[k];
    aux[cur[b] + (k - scn[b])] = sorted[k];
  }
}

// ---------------- merged CSR finalize ----------------
__global__ __launch_bounds__(256) void k_csr(const int* __restrict__ gcur,
                                             const int* __restrict__ aux,
                                             int* __restrict__ row_ptr,
                                             float* __restrict__ dinv,
                                             int* __restrict__ col) {
  __shared__ int red[256];
  __shared__ int c[128];
  __shared__ int cur[128];
  const int b = blockIdx.x, t = threadIdx.x;
  int p = 0;
  for (int i = t; i < b; i += 256) p += gcur[i] - i * BCAP;
  red[t] = p;
  if (t < 128) c[t] = 0;
  __syncthreads();
  for (int off = 128; off > 0; off >>= 1) {
    if (t < off) red[t] += red[t + off];
    __syncthreads();
  }
  const int base = red[0];
  const int m = gcur[b] - b * BCAP;
  const int* a = aux + (size_t)b * BCAP;
  __syncthreads();
  for (int k = t; k < m; k += 256) atomicAdd(&c[a[k] >> 17], 1);
  __syncthreads();
  int val = (t < 128) ? c[t] : 0;
  red[t] = val;
  __syncthreads();
  for (int off = 1; off < 128; off <<= 1) {
    int add = (t >= off && t < 128) ? red[t - off] : 0;
    __syncthreads();
    if (t < 128) red[t] += add;
    __syncthreads();
  }
  if (t < 128) {
    int excl = red[t] - val + base;
    int node = b * 128 + t;
    if (node < NN) {
      row_ptr[node] = excl;
      dinv[node] = rsqrtf((float)(val + 1));
      cur[t] = excl;
    }
  }
  if (b == NBKT - 1 && t == 0) row_ptr[NN] = base + m;
  __syncthreads();
  for (int k = t; k < m; k += 256) {
    int pk2 = a[k];
    int pos = atomicAdd(&cur[pk2 >> 17], 1);
    col[pos] = pk2 & 0x1FFFF;
  }
}

// ---------------- MFMA GEMM (padding rows written as zeros) ----------------
template <int COUT, bool AFP32>
__global__ __launch_bounds__(256) void k_gemm_mfma(const void* __restrict__ Av,
                                                   const uint* __restrict__ Wt,
                                                   const float* __restrict__ dinv,
                                                   unsigned short* __restrict__ T) {
  constexpr int NT = COUT / 16;
  __shared__ __align__(16) uint Wlds[4 * NT * 64 * 4];
  __shared__ __align__(16) unsigned short Obuf[64 * COUT];
  const int t = threadIdx.x;
  {
    const uint4* src = (const uint4*)Wt;
    uint4* dst = (uint4*)Wlds;
    for (int i = t; i < 4 * NT * 64; i += 256) dst[i] = src[i];
  }
  __syncthreads();

  const int wv = t >> 6, lane = t & 63;
  const int n = lane & 15, quad = lane >> 4;
  const int rbase = blockIdx.x * 64 + wv * 16;

  union AB { uint4 u; s16x8 s; };
  AB a[4];
  if constexpr (AFP32) {
    const float* A = (const float*)Av;
    int row = rbase + n;
    if (row >= NN) row = NN - 1;  // input x is exactly NN rows
    const float* ap = A + (size_t)row * 128;
#pragma unroll
    for (int ks = 0; ks < 4; ++ks) {
      float4 v0 = *(const float4*)(ap + ks * 32 + quad * 8);
      float4 v1 = *(const float4*)(ap + ks * 32 + quad * 8 + 4);
      a[ks].u.x = (uint)f2bf(v0.x) | ((uint)f2bf(v0.y) << 16);
      a[ks].u.y = (uint)f2bf(v0.z) | ((uint)f2bf(v0.w) << 16);
      a[ks].u.z = (uint)f2bf(v1.x) | ((uint)f2bf(v1.y) << 16);
      a[ks].u.w = (uint)f2bf(v1.z) | ((uint)f2bf(v1.w) << 16);
    }
  } else {
    const uint4* A = (const uint4*)Av;
    int row = rbase + n;  // ws rows padded to NNP: in-bounds (values unused for pads)
#pragma unroll
    for (int ks = 0; ks < 4; ++ks) a[ks].u = A[(size_t)row * 16 + ks * 4 + quad];
  }

  f32x4 acc[NT];
#pragma unroll
  for (int tl = 0; tl < NT; ++tl) acc[tl] = (f32x4){0.f, 0.f, 0.f, 0.f};

#pragma unroll
  for (int ks = 0; ks < 4; ++ks) {
#pragma unroll
    for (int tl = 0; tl < NT; ++tl) {
      AB b;
      b.u = *(const uint4*)&Wlds[((ks * NT + tl) * 64 + lane) * 4];
      acc[tl] = __builtin_amdgcn_mfma_f32_16x16x32_bf16(a[ks].s, b.s, acc[tl], 0, 0, 0);
    }
  }

  float4 dv = *(const float4*)(dinv + rbase + quad * 4);
  float dvv[4] = {dv.x, dv.y, dv.z, dv.w};
  unsigned short* ob = Obuf + wv * 16 * COUT;
#pragma unroll
  for (int tl = 0; tl < NT; ++tl)
#pragma unroll
    for (int r = 0; r < 4; ++r)
      ob[(quad * 4 + r) * COUT + tl * 16 + n] = f2bf(acc[tl][r] * dvv[r]);

  // padding rows (>=NN) get explicit zeros -> row NN is a safe zero row for
  // the gathers' clamped loads.
  uint4* gdst = (uint4*)(T + (size_t)rbase * COUT);
  constexpr int ITER = COUT / 32;
#pragma unroll
  for (int i = 0; i < ITER; ++i) {
    int off16 = i * 64 + lane;
    int lrow = (off16 * 8) / COUT;
    uint4 v = make_uint4(0u, 0u, 0u, 0u);
    if (rbase + lrow < NN) v = *(const uint4*)&ob[off16 * 8];
    gdst[off16] = v;
  }
}

// ---------------- gather layers 1/2: uniform-trip clamped loop -------------
// An[i] = bf16(relu(dinv[i]*(T[i]+sum T[col])+b)). All edges go through the
// 4-deep unrolled path; out-of-range slots clamp to zero row NN.
__global__ __launch_bounds__(256) void k_gather12(const int* __restrict__ row_ptr,
                                                  const int* __restrict__ col,
                                                  const uint4* __restrict__ T4,
                                                  const float* __restrict__ dinv,
                                                  const float* __restrict__ bias,
                                                  uint4* __restrict__ An) {
  int w = (blockIdx.x * 256 + threadIdx.x) >> 6;
  int lane = threadIdx.x & 63;
  if (w >= NN) return;
  int s = row_ptr[w], tend = row_ptr[w + 1];
  const int q = lane >> 4;   // edge group 0..3
  const int cl = lane & 15;  // uint4 (8 channels) within 256B row
  float acc[8] = {0.f, 0.f, 0.f, 0.f, 0.f, 0.f, 0.f, 0.f};
  if (q == 0) {
    uint4 u = T4[(size_t)w * 16 + cl];  // self-loop term
    upadd(u.x, acc[0], acc[1]);
    upadd(u.y, acc[2], acc[3]);
    upadd(u.z, acc[4], acc[5]);
    upadd(u.w, acc[6], acc[7]);
  }
  const int iters = (tend - s + 15) >> 4;
  const int m = tend - 1;
  int e = s + q;
  for (int it = 0; it < iters; ++it, e += 16) {
    int i0 = e, i1 = e + 4, i2 = e + 8, i3 = e + 12;
    int c0 = col[min(i0, m)], c1 = col[min(i1, m)];
    int c2 = col[min(i2, m)], c3 = col[min(i3, m)];
    c0 = (i0 < tend) ? c0 : NN;
    c1 = (i1 < tend) ? c1 : NN;
    c2 = (i2 < tend) ? c2 : NN;
    c3 = (i3 < tend) ? c3 : NN;
    uint4 v0 = T4[(size_t)c0 * 16 + cl];
    uint4 v1 = T4[(size_t)c1 * 16 + cl];
    uint4 v2 = T4[(size_t)c2 * 16 + cl];
    uint4 v3 = T4[(size_t)c3 * 16 + cl];
    upadd(v0.x, acc[0], acc[1]); upadd(v0.y, acc[2], acc[3]);
    upadd(v0.z, acc[4], acc[5]); upadd(v0.w, acc[6], acc[7]);
    upadd(v1.x, acc[0], acc[1]); upadd(v1.y, acc[2], acc[3]);
    upadd(v1.z, acc[4], acc[5]); upadd(v1.w, acc[6], acc[7]);
    upadd(v2.x, acc[0], acc[1]); upadd(v2.y, acc[2], acc[3]);
    upadd(v2.z, acc[4], acc[5]); upadd(v2.w, acc[6], acc[7]);
    upadd(v3.x, acc[0], acc[1]); upadd(v3.y, acc[2], acc[3]);
    upadd(v3.z, acc[4], acc[5]); upadd(v3.w, acc[6], acc[7]);
  }
#pragma unroll
  for (int i = 0; i < 8; ++i) {
    acc[i] += __shfl_down(acc[i], 16, 64);
    acc[i] += __shfl_down(acc[i], 32, 64);
  }
  if (q == 0) {
    float4 b0 = *(const float4*)&bias[cl * 8];
    float4 b1 = *(const float4*)&bias[cl * 8 + 4];
    float dv = dinv[w];
    float r[8];
    r[0] = fmaxf(fmaf(dv, acc[0], b0.x), 0.f);
    r[1] = fmaxf(fmaf(dv, acc[1], b0.y), 0.f);
    r[2] = fmaxf(fmaf(dv, acc[2], b0.z), 0.f);
    r[3] = fmaxf(fmaf(dv, acc[3], b0.w), 0.f);
    r[4] = fmaxf(fmaf(dv, acc[4], b1.x), 0.f);
    r[5] = fmaxf(fmaf(dv, acc[5], b1.y), 0.f);
    r[6] = fmaxf(fmaf(dv, acc[6], b1.z), 0.f);
    r[7] = fmaxf(fmaf(dv, acc[7], b1.w), 0.f);
    uint4 o;
    o.x = (uint)f2bf(r[0]) | ((uint)f2bf(r[1]) << 16);
    o.y = (uint)f2bf(r[2]) | ((uint)f2bf(r[3]) << 16);
    o.z = (uint)f2bf(r[4]) | ((uint)f2bf(r[5]) << 16);
    o.w = (uint)f2bf(r[6]) | ((uint)f2bf(r[7]) << 16);
    An[(size_t)w * 16 + cl] = o;
  }
}

// ---------------- gather layer 3: uniform-trip clamped, fp32 out ----------
__global__ __launch_bounds__(256) void k_gather3(const int* __restrict__ row_ptr,
                                                 const int* __restrict__ col,
                                                 const uint4* __restrict__ T4,
                                                 float* __restrict__ G3) {
  int w = (blockIdx.x * 256 + threadIdx.x) >> 6;
  int lane = threadIdx.x & 63;
  if (w >= NN) return;
  int s = row_ptr[w], tend = row_ptr[w + 1];
  const int g = lane >> 3;  // edge group 0..7
  const int cl = lane & 7;  // uint4 (8 channels) within 128B row
  float acc[8] = {0.f, 0.f, 0.f, 0.f, 0.f, 0.f, 0.f, 0.f};
  if (g == 0) {
    uint4 u = T4[(size_t)w * 8 + cl];
    upadd(u.x, acc[0], acc[1]);
    upadd(u.y, acc[2], acc[3]);
    upadd(u.z, acc[4], acc[5]);
    upadd(u.w, acc[6], acc[7]);
  }
  const int iters = (tend - s + 15) >> 4;
  const int m = tend - 1;
  int e = s + g;
  for (int it = 0; it < iters; ++it, e += 16) {
    int i0 = e, i1 = e + 8;
    int c0 = col[min(i0, m)], c1 = col[min(i1, m)];
    c0 = (i0 < tend) ? c0 : NN;
    c1 = (i1 < tend) ? c1 : NN;
    uint4 v0 = T4[(size_t)c0 * 8 + cl];
    uint4 v1 = T4[(size_t)c1 * 8 + cl];
    upadd(v0.x, acc[0], acc[1]); upadd(v0.y, acc[2], acc[3]);
    upadd(v0.z, acc[4], acc[5]); upadd(v0.w, acc[6], acc[7]);
    upadd(v1.x, acc[0], acc[1]); upadd(v1.y, acc[2], acc[3]);
    upadd(v1.z, acc[4], acc[5]); upadd(v1.w, acc[6], acc[7]);
  }
#pragma unroll
  for (int i = 0; i < 8; ++i) {
    acc[i] += __shfl_down(acc[i], 8, 64);
    acc[i] += __shfl_down(acc[i], 16, 64);
    acc[i] += __shfl_down(acc[i], 32, 64);
  }
  if (g == 0) {
    float* gp = &G3[(size_t)w * 64 + cl * 8];
    *(float4*)gp = make_float4(acc[0], acc[1], acc[2], acc[3]);
    *(float4*)(gp + 4) = make_float4(acc[4], acc[5], acc[6], acc[7]);
  }
}

// ---------------- pair decode: 4 pairs/wave ----------------
__global__ __launch_bounds__(256) void k_decode(const int* __restrict__ ni,
                                                const int* __restrict__ nj,
                                                const float* __restrict__ G3,
                                                const float* __restrict__ dinv,
                                                const float* __restrict__ b3,
                                                float* __restrict__ out) {
  int p = blockIdx.x * 16 + (threadIdx.x >> 4);
  int cl = threadIdx.x & 15;
  int i = ni[p], j = nj[p];
  float4 gi = *(const float4*)&G3[(size_t)i * 64 + cl * 4];
  float4 gj = *(const float4*)&G3[(size_t)j * 64 + cl * 4];
  float4 bb = *(const float4*)&b3[cl * 4];
  float di = dinv[i], dj = dinv[j];
  float v = fmaf(di, gi.x, bb.x) * fmaf(dj, gj.x, bb.x) +
            fmaf(di, gi.y, bb.y) * fmaf(dj, gj.y, bb.y) +
            fmaf(di, gi.z, bb.z) * fmaf(dj, gj.z, bb.z) +
            fmaf(di, gi.w, bb.w) * fmaf(dj, gj.w, bb.w);
  v += __shfl_xor(v, 1, 64);
  v += __shfl_xor(v, 2, 64);
  v += __shfl_xor(v, 4, 64);
  v += __shfl_xor(v, 8, 64);
  if (cl == 0) out[p] = v;
}

extern "C" void kernel_launch(void* const* d_in, const int* in_sizes, int n_in,
                              void* d_out, int out_size, void* d_ws, size_t ws_size,
                              hipStream_t stream) {
  const float* x  = (const float*)d_in[0];
  const int*   ei = (const int*)d_in[1];
  const int*   ni = (const int*)d_in[2];
  const int*   nj = (const int*)d_in[3];
  const float* W1 = (const float*)d_in[4];
  const float* b1 = (const float*)d_in[5];
  const float* W2 = (const float*)d_in[6];
  const float* b2 = (const float*)d_in[7];
  const float* W3 = (const float*)d_in[8];
  const float* b3 = (const float*)d_in[9];
  float* out = (float*)d_out;

  // ws carve (4-byte words)
  float* dinv    = (float*)d_ws;              // 102400
  int*   row_ptr = (int*)(dinv + 102400);     // 102400 (NN+1 used)
  int*   gcur    = row_ptr + 102400;          // 1024
  int*   col     = gcur + 1024;               // NE
  uint*  Wt1     = (uint*)(col + NE);         // 8192
  uint*  Wt2     = Wt1 + 8192;                // 8192
  uint*  Wt3     = Wt2 + 8192;                // 4096
  uint*  Tbf     = Wt3 + 4096;                // NNP*64 (bf16 [NNP][128])
  uint*  Abf     = Tbf + (size_t)NNP * 64;    // NNP*64
  float* G3      = (float*)(Abf + (size_t)NNP * 64);  // NNP*64 fp32
  int*   aux     = (int*)G3;  // 12.6 MB arena, dead before gather3 writes G3

  // ---- setup (gcur + weight pre-pack) + CSR build ----
  k_setup<<<24, 256, 0, stream>>>(W1, W2, W3, Wt1, Wt2, Wt3, gcur);
  k_bucket<<<(NE + BKB - 1) / BKB, 256, 0, stream>>>(ei, gcur, aux);
  k_csr<<<NBKT, 256, 0, stream>>>(gcur, aux, row_ptr, dinv, col);

  const int GB = NNP / 64;                 // 1563
  const int GATB = (NN * 64 + 255) / 256;  // 25000

  // layer 1 (x fp32 -> Tbf bf16)
  k_gemm_mfma<128, true><<<GB, 256, 0, stream>>>(x, Wt1, dinv, (unsigned short*)Tbf);
  k_gather12<<<GATB, 256, 0, stream>>>(row_ptr, col, (const uint4*)Tbf, dinv, b1, (uint4*)Abf);
  // layer 2
  k_gemm_mfma<128, false><<<GB, 256, 0, stream>>>(Abf, Wt2, dinv, (unsigned short*)Tbf);
  k_gather12<<<GATB, 256, 0, stream>>>(row_ptr, col, (const uint4*)Tbf, dinv, b2, (uint4*)Abf);
  // layer 3 (COUT=64)
  k_gemm_mfma<64, false><<<GB, 256, 0, stream>>>(Abf, Wt3, dinv, (unsigned short*)Tbf);
  k_gather3<<<GATB, 256, 0, stream>>>(row_ptr, col, (const uint4*)Tbf, G3);
  // decode
  k_decode<<<NP / 16, 256, 0, stream>>>(ni, nj, G3, dinv, b3, out);
}